// Round 4
// baseline (358.567 us; speedup 1.0000x reference)
//
#include <hip/hip_runtime.h>

#define F_IN  384
#define EPB   4096   // edges per block, pass 1
#define NBINS 256    // dsts per coarse bucket
#define BCAP  12288  // eidx region stride per bucket (avg 8163, huge safety margin)
#define SDS   208    // segdesc row stride (u16 entries), >= NBK+1

// ---------------- pass 1: coarse bucket partition (dst>>8), atomic-free ----------------

__launch_bounds__(256)
__global__ void k_p1(const int* __restrict__ ei, int E, int NBK,
                     unsigned* __restrict__ packed, unsigned short* __restrict__ segdesc) {
    __shared__ unsigned sin[EPB];
    __shared__ unsigned sout[EPB];
    __shared__ int hist[257], cur[256], excl[257];
    const int t = threadIdx.x;
    const int e0 = blockIdx.x * EPB;
    const int cnt = min(EPB, E - e0);

    if (t < 256) { hist[t] = 0; cur[t] = 0; }
    if (t == 0) hist[256] = 0;
    __syncthreads();

    for (int i = t; i < cnt; i += 256) {
        int s = ei[e0 + i];
        int d = ei[E + e0 + i];
        sin[i] = ((unsigned)d << 16) | (unsigned)s;   // N < 65536 for both
        atomicAdd(&hist[d >> 8], 1);
    }
    __syncthreads();

    if (t < 64) {  // wave 0: exclusive scan of hist[0..NBK)
        int carry = 0;
        for (int c = 0; c * 64 < NBK; ++c) {
            int idx = c * 64 + t;
            int v = (idx < NBK) ? hist[idx] : 0;
            int x = v;
#pragma unroll
            for (int d = 1; d < 64; d <<= 1) { int y = __shfl_up(x, d, 64); if (t >= d) x += y; }
            if (idx < NBK) excl[idx] = carry + x - v;
            carry += __shfl(x, 63, 64);
        }
        if (t == 0) excl[NBK] = carry;   // == cnt
    }
    __syncthreads();

    for (int i = t; i < cnt; i += 256) {
        unsigned v = sin[i];
        int b = v >> 24;                 // dst >> 8
        int pos = excl[b] + atomicAdd(&cur[b], 1);   // LDS atomic (fast)
        sout[pos] = v;
    }
    __syncthreads();

    for (int i = t; i < cnt; i += 256) packed[(size_t)e0 + i] = sout[i];   // coalesced
    for (int i = t; i <= NBK; i += 256) segdesc[(size_t)blockIdx.x * SDS + i] = (unsigned short)excl[i];
}

// ---------------- pass 2: per-bucket exact CSR (rpB/rpE/dinv/eidx), all in LDS ----------------

__launch_bounds__(256)
__global__ void k_p2(const unsigned* __restrict__ packed, const unsigned short* __restrict__ segdesc,
                     int NB1, unsigned short* __restrict__ eidx,
                     int* __restrict__ rpB, int* __restrict__ rpE,
                     float* __restrict__ dinv, int N) {
    __shared__ unsigned ev[BCAP];
    __shared__ unsigned short se[BCAP];
    __shared__ int lenS[512], offS[513];
    __shared__ int hist[NBINS], cur[NBINS], excl[NBINS + 1];
    const int t = threadIdx.x;
    const int b = blockIdx.x;

    if (t < NBINS) { hist[t] = 0; cur[t] = 0; }
    for (int blk = t; blk < NB1; blk += 256) {
        int s0 = segdesc[(size_t)blk * SDS + b];
        int s1 = segdesc[(size_t)blk * SDS + b + 1];
        lenS[blk] = s1 - s0;
    }
    __syncthreads();

    if (t < 64) {  // wave 0: exclusive scan of lenS[0..NB1)
        int carry = 0;
        for (int c = 0; c * 64 < NB1; ++c) {
            int idx = c * 64 + t;
            int v = (idx < NB1) ? lenS[idx] : 0;
            int x = v;
#pragma unroll
            for (int d = 1; d < 64; d <<= 1) { int y = __shfl_up(x, d, 64); if (t >= d) x += y; }
            if (idx < NB1) offS[idx] = carry + x - v;
            carry += __shfl(x, 63, 64);
        }
        if (t == 0) offS[NB1 < 512 ? NB1 : 512] = carry;
    }
    __syncthreads();
    const int total = min(offS[NB1 < 512 ? NB1 : 512], BCAP);

    for (int blk = t; blk < NB1; blk += 256) {
        int s0 = segdesc[(size_t)blk * SDS + b];
        int l = lenS[blk], o = offS[blk];
        if (o + l > BCAP) l = max(0, BCAP - o);
        const unsigned* sp = packed + (size_t)blk * EPB + s0;
        for (int j = 0; j < l; ++j) ev[o + j] = sp[j];
    }
    __syncthreads();

    for (int i = t; i < total; i += 256) atomicAdd(&hist[(ev[i] >> 16) & 0xFF], 1);
    __syncthreads();

    if (t < 64) {  // wave 0: exclusive scan of hist[0..256)
        int carry = 0;
#pragma unroll
        for (int c = 0; c < 4; ++c) {
            int idx = c * 64 + t;
            int v = hist[idx];
            int x = v;
#pragma unroll
            for (int d = 1; d < 64; d <<= 1) { int y = __shfl_up(x, d, 64); if (t >= d) x += y; }
            excl[idx] = carry + x - v;
            carry += __shfl(x, 63, 64);
        }
        if (t == 0) excl[NBINS] = carry;
    }
    __syncthreads();

    if (t < NBINS) {
        int d = b * NBINS + t;
        if (d < N) {
            int c = hist[t];
            int base = b * BCAP + excl[t];
            rpB[d] = base;
            rpE[d] = base + c;
            dinv[d] = rsqrtf((float)(c + 1));   // +1 self-loop
        }
    }
    for (int i = t; i < total; i += 256) {
        unsigned v = ev[i];
        int l = (v >> 16) & 0xFF;
        int p = excl[l] + atomicAdd(&cur[l], 1);
        se[p] = (unsigned short)(v & 0xFFFF);
    }
    __syncthreads();
    for (int i = t; i < total; i += 256) eidx[(size_t)b * BCAP + i] = se[i];
}

// ---------------- GEMM1: m1p = (x @ W1) * dinv[row] ----------------

__launch_bounds__(256)
__global__ void k_gemm1(const float* __restrict__ x, const float* __restrict__ W1,
                        const float* __restrict__ dinv,
                        float* __restrict__ m1p, int N) {
    __shared__ float xtT[32][68];
    __shared__ float wt[32][64];
    const int t  = threadIdx.x;
    const int tx = t & 15;
    const int ty = t >> 4;
    const int row0 = blockIdx.x * 64;

    float acc[4][4];
#pragma unroll
    for (int i = 0; i < 4; i++)
#pragma unroll
        for (int j = 0; j < 4; j++) acc[i][j] = 0.f;

    for (int k0 = 0; k0 < F_IN; k0 += 32) {
        __syncthreads();
#pragma unroll
        for (int l = 0; l < 2; l++) {
            int f4 = t + l * 256;
            {
                int r = f4 >> 3, c = (f4 & 7) << 2;
                int row = row0 + r;
                float4 v = make_float4(0.f, 0.f, 0.f, 0.f);
                if (row < N) v = *reinterpret_cast<const float4*>(&x[(size_t)row * F_IN + k0 + c]);
                xtT[c + 0][r] = v.x; xtT[c + 1][r] = v.y; xtT[c + 2][r] = v.z; xtT[c + 3][r] = v.w;
            }
            {
                int r = f4 >> 4, c = (f4 & 15) << 2;
                float4 v = *reinterpret_cast<const float4*>(&W1[(k0 + r) * 64 + c]);
                wt[r][c] = v.x; wt[r][c + 1] = v.y; wt[r][c + 2] = v.z; wt[r][c + 3] = v.w;
            }
        }
        __syncthreads();
#pragma unroll
        for (int kk = 0; kk < 32; kk++) {
            float4 xv = *reinterpret_cast<const float4*>(&xtT[kk][ty << 2]);
            float4 wv = *reinterpret_cast<const float4*>(&wt[kk][tx << 2]);
            acc[0][0] += xv.x * wv.x; acc[0][1] += xv.x * wv.y; acc[0][2] += xv.x * wv.z; acc[0][3] += xv.x * wv.w;
            acc[1][0] += xv.y * wv.x; acc[1][1] += xv.y * wv.y; acc[1][2] += xv.y * wv.z; acc[1][3] += xv.y * wv.w;
            acc[2][0] += xv.z * wv.x; acc[2][1] += xv.z * wv.y; acc[2][2] += xv.z * wv.z; acc[2][3] += xv.z * wv.w;
            acc[3][0] += xv.w * wv.x; acc[3][1] += xv.w * wv.y; acc[3][2] += xv.w * wv.z; acc[3][3] += xv.w * wv.w;
        }
    }
#pragma unroll
    for (int i = 0; i < 4; i++) {
        int row = row0 + (ty << 2) + i;
        if (row < N) {
            float s = dinv[row];
            float4 v = make_float4(acc[i][0] * s, acc[i][1] * s, acc[i][2] * s, acc[i][3] * s);
            *reinterpret_cast<float4*>(&m1p[(size_t)row * 64 + (tx << 2)]) = v;
        }
    }
}

// ---------------- CSR gather, 64 features: one wave per node ----------------

__launch_bounds__(256)
__global__ void k_gather64(const int* __restrict__ rpB, const int* __restrict__ rpE,
                           const unsigned short* __restrict__ eidx,
                           const float* __restrict__ msg, float* __restrict__ acc, int N) {
    int w = blockIdx.x * 4 + (threadIdx.x >> 6);
    if (w >= N) return;
    int f = threadIdx.x & 63;
    int i = rpB[w], e = rpE[w];
    float a0 = msg[(size_t)w * 64 + f];   // self-loop message
    float a1 = 0.f, a2 = 0.f, a3 = 0.f;
    for (; i + 4 <= e; i += 4) {
        int s0 = eidx[i], s1 = eidx[i + 1], s2 = eidx[i + 2], s3 = eidx[i + 3];
        a0 += msg[(size_t)s0 * 64 + f];
        a1 += msg[(size_t)s1 * 64 + f];
        a2 += msg[(size_t)s2 * 64 + f];
        a3 += msg[(size_t)s3 * 64 + f];
    }
    for (; i < e; i++) a0 += msg[(size_t)eidx[i] * 64 + f];
    acc[(size_t)w * 64 + f] = (a0 + a1) + (a2 + a3);
}

// ---------------- CSR gather, 32 features (optional fused relu/bias/scale epilogue) ----------------

__launch_bounds__(256)
__global__ void k_gather32(const int* __restrict__ rpB, const int* __restrict__ rpE,
                           const unsigned short* __restrict__ eidx,
                           const float* __restrict__ msg, float* __restrict__ outp, int N,
                           const float* __restrict__ bias, const float* __restrict__ dinv) {
    int w = blockIdx.x * 8 + (threadIdx.x >> 5);
    if (w >= N) return;
    int f = threadIdx.x & 31;
    int i = rpB[w], e = rpE[w];
    float a0 = msg[(size_t)w * 32 + f];
    float a1 = 0.f, a2 = 0.f, a3 = 0.f;
    for (; i + 4 <= e; i += 4) {
        int s0 = eidx[i], s1 = eidx[i + 1], s2 = eidx[i + 2], s3 = eidx[i + 3];
        a0 += msg[(size_t)s0 * 32 + f];
        a1 += msg[(size_t)s1 * 32 + f];
        a2 += msg[(size_t)s2 * 32 + f];
        a3 += msg[(size_t)s3 * 32 + f];
    }
    for (; i < e; i++) a0 += msg[(size_t)eidx[i] * 32 + f];
    float r = (a0 + a1) + (a2 + a3);
    if (bias) {  // fused mid-layer: h' = relu(r*s + b) * s
        float s = dinv[w];
        r = fmaxf(r * s + bias[f], 0.f) * s;
    }
    outp[(size_t)w * 32 + f] = r;
}

// ---------------- layer2: h1 = relu(s*acc1 + b1); m2p = (h1@W2)*s ----------------

__launch_bounds__(256)
__global__ void k_layer2(const float* __restrict__ acc1, const float* __restrict__ W2,
                         const float* __restrict__ b1, const float* __restrict__ dinv,
                         float* __restrict__ m2p, int N) {
    __shared__ float h1t[64][64];
    __shared__ float w2t[64][32];
    const int t = threadIdx.x;
    const int row0 = blockIdx.x * 64;
#pragma unroll
    for (int i = 0; i < 16; i++) {
        int lin = i * 256 + t;
        int r = lin >> 6, c = lin & 63;
        int row = row0 + r;
        float v = 0.f;
        if (row < N) v = fmaxf(acc1[(size_t)row * 64 + c] * dinv[row] + b1[c], 0.f);
        h1t[r][c] = v;
    }
#pragma unroll
    for (int i = 0; i < 8; i++) {
        int lin = i * 256 + t;
        w2t[lin >> 5][lin & 31] = W2[lin];
    }
    __syncthreads();
    const int tx = t & 31, ty = t >> 5;
#pragma unroll
    for (int rr = 0; rr < 8; rr++) {
        int r = rr * 8 + ty;
        float a = 0.f;
#pragma unroll
        for (int k = 0; k < 64; k++) a += h1t[r][k] * w2t[k][tx];
        int row = row0 + r;
        if (row < N) m2p[(size_t)row * 32 + tx] = a * dinv[row];
    }
}

// ---------------- out GEMM: out = (dinv*acc3) @ W3 + b3; sigmoid col 0 ----------------
// 64 rows x 64 cols per block, 256 threads, 4x4 register tile, K=32 in one LDS stage.

__launch_bounds__(256)
__global__ void k_out(const float* __restrict__ acc3, const float* __restrict__ W3,
                      const float* __restrict__ b3, const float* __restrict__ dinv,
                      float* __restrict__ out, int N) {
    __shared__ float gt[32][68];   // transposed g-tile: [k][row], stride 68 keeps 16B alignment
    __shared__ float wt[32][64];   // W3 tile: [k][col]
    const int t  = threadIdx.x;
    const int tx = t & 15;         // col group (4 cols)
    const int ty = t >> 4;         // row group (4 rows)
    const int row0 = blockIdx.x * 64;
    const int col0 = blockIdx.y * 64;

    // stage g-tile: 64 rows x 32 k, scaled by dinv[row], transposed into gt
#pragma unroll
    for (int l = 0; l < 2; l++) {
        int f4 = t + l * 256;                 // 0..511
        int r = f4 >> 3, c = (f4 & 7) << 2;   // row-in-tile, k
        int row = row0 + r;
        float4 v = make_float4(0.f, 0.f, 0.f, 0.f);
        float s = 0.f;
        if (row < N) { v = *reinterpret_cast<const float4*>(&acc3[(size_t)row * 32 + c]); s = dinv[row]; }
        gt[c + 0][r] = v.x * s; gt[c + 1][r] = v.y * s; gt[c + 2][r] = v.z * s; gt[c + 3][r] = v.w * s;
    }
    // stage W3 tile: 32 k x 64 cols (scalar, row stride 385 is odd -> no vec alignment)
#pragma unroll
    for (int l = 0; l < 8; l++) {
        int lin = t + l * 256;                // 0..2047
        int r = lin >> 6, c = lin & 63;
        int col = col0 + c;
        wt[r][c] = (col < 385) ? W3[(size_t)r * 385 + col] : 0.f;
    }
    float bias_r[4];
#pragma unroll
    for (int j = 0; j < 4; j++) {
        int col = col0 + (tx << 2) + j;
        bias_r[j] = (col < 385) ? b3[col] : 0.f;
    }
    __syncthreads();

    float acc[4][4];
#pragma unroll
    for (int i = 0; i < 4; i++)
#pragma unroll
        for (int j = 0; j < 4; j++) acc[i][j] = 0.f;

#pragma unroll
    for (int kk = 0; kk < 32; kk++) {
        float4 gv = *reinterpret_cast<const float4*>(&gt[kk][ty << 2]);
        float4 wv = *reinterpret_cast<const float4*>(&wt[kk][tx << 2]);
        acc[0][0] += gv.x * wv.x; acc[0][1] += gv.x * wv.y; acc[0][2] += gv.x * wv.z; acc[0][3] += gv.x * wv.w;
        acc[1][0] += gv.y * wv.x; acc[1][1] += gv.y * wv.y; acc[1][2] += gv.y * wv.z; acc[1][3] += gv.y * wv.w;
        acc[2][0] += gv.z * wv.x; acc[2][1] += gv.z * wv.y; acc[2][2] += gv.z * wv.z; acc[2][3] += gv.z * wv.w;
        acc[3][0] += gv.w * wv.x; acc[3][1] += gv.w * wv.y; acc[3][2] += gv.w * wv.z; acc[3][3] += gv.w * wv.w;
    }

#pragma unroll
    for (int i = 0; i < 4; i++) {
        int row = row0 + (ty << 2) + i;
        if (row < N) {
            size_t base = (size_t)row * 385;
#pragma unroll
            for (int j = 0; j < 4; j++) {
                int col = col0 + (tx << 2) + j;
                if (col < 385) {
                    float a = acc[i][j] + bias_r[j];
                    if (col == 0) a = 1.0f / (1.0f + expf(-a));
                    out[base + col] = a;
                }
            }
        }
    }
}

extern "C" void kernel_launch(void* const* d_in, const int* in_sizes, int n_in,
                              void* d_out, int out_size, void* d_ws, size_t ws_size,
                              hipStream_t stream) {
    const float* x  = (const float*)d_in[0];
    const int*   ei = (const int*)d_in[1];
    const float* W1 = (const float*)d_in[2];
    const float* b1 = (const float*)d_in[3];
    const float* W2 = (const float*)d_in[4];
    const float* b2 = (const float*)d_in[5];
    const float* W3 = (const float*)d_in[6];
    const float* b3 = (const float*)d_in[7];
    float* out = (float*)d_out;

    const int N = in_sizes[0] / F_IN;   // 50000
    const int E = in_sizes[1] / 2;      // 1600000
    const int NB1 = (E + EPB - 1) / EPB;       // 391 pass-1 blocks
    const int NBK = (N + NBINS - 1) / NBINS;   // 196 coarse buckets

    float* ws   = (float*)d_ws;
    float* dinv = ws;
    float* bufA = ws + N;
    float* bufB = bufA + (size_t)64 * N;
    int*   rpB  = (int*)(bufB + (size_t)64 * N);
    int*   rpE  = rpB + N;
    unsigned short* eidx    = (unsigned short*)(rpE + N);
    unsigned short* segdesc = eidx + (size_t)NBK * BCAP;

    unsigned* packed = (unsigned*)bufA;   // E u32 <= 64N floats; dead after k_p2
    float* m1p  = bufA;   // [N,64]
    float* acc1 = bufB;   // [N,64]
    float* m2p  = bufA;   // [N,32]
    float* h2p  = bufB;   // [N,32]
    float* acc3 = bufA;   // [N,32]

    k_p1<<<NB1, 256, 0, stream>>>(ei, E, NBK, packed, segdesc);
    k_p2<<<NBK, 256, 0, stream>>>(packed, segdesc, NB1, eidx, rpB, rpE, dinv, N);

    k_gemm1   <<<(N + 63) / 64, 256, 0, stream>>>(x, W1, dinv, m1p, N);
    k_gather64<<<(N + 3) / 4, 256, 0, stream>>>(rpB, rpE, eidx, m1p, acc1, N);

    k_layer2  <<<(N + 63) / 64, 256, 0, stream>>>(acc1, W2, b1, dinv, m2p, N);
    k_gather32<<<(N + 7) / 8, 256, 0, stream>>>(rpB, rpE, eidx, m2p, h2p, N, b2, dinv);   // fused mid3

    k_gather32<<<(N + 7) / 8, 256, 0, stream>>>(rpB, rpE, eidx, h2p, acc3, N, nullptr, dinv);

    dim3 gout((N + 63) / 64, (385 + 63) / 64);
    k_out     <<<gout, 256, 0, stream>>>(acc3, W3, b3, dinv, out, N);
}

// Round 5
// 293.636 us; speedup vs baseline: 1.2211x; 1.2211x over previous
//
#include <hip/hip_runtime.h>

#define F_IN  384
#define EPB   4096   // edges per block, pass 1
#define NBINS 256    // dsts per coarse bucket
#define BCAP  12288  // eidx region stride per bucket (avg 8163, huge safety margin)
#define SDS   208    // segdesc row stride (u16 entries), >= NBK+1

// ---------------- pass 1: coarse bucket partition (dst>>8), atomic-free ----------------

__launch_bounds__(256)
__global__ void k_p1(const int* __restrict__ ei, int E, int NBK,
                     unsigned* __restrict__ packed, unsigned short* __restrict__ segdesc) {
    __shared__ unsigned sin[EPB];
    __shared__ unsigned sout[EPB];
    __shared__ int hist[257], cur[256], excl[257];
    const int t = threadIdx.x;
    const int e0 = blockIdx.x * EPB;
    const int cnt = min(EPB, E - e0);

    if (t < 256) { hist[t] = 0; cur[t] = 0; }
    if (t == 0) hist[256] = 0;
    __syncthreads();

    for (int i = t; i < cnt; i += 256) {
        int s = ei[e0 + i];
        int d = ei[E + e0 + i];
        sin[i] = ((unsigned)d << 16) | (unsigned)s;   // N < 65536 for both
        atomicAdd(&hist[d >> 8], 1);
    }
    __syncthreads();

    if (t < 64) {  // wave 0: exclusive scan of hist[0..NBK)
        int carry = 0;
        for (int c = 0; c * 64 < NBK; ++c) {
            int idx = c * 64 + t;
            int v = (idx < NBK) ? hist[idx] : 0;
            int x = v;
#pragma unroll
            for (int d = 1; d < 64; d <<= 1) { int y = __shfl_up(x, d, 64); if (t >= d) x += y; }
            if (idx < NBK) excl[idx] = carry + x - v;
            carry += __shfl(x, 63, 64);
        }
        if (t == 0) excl[NBK] = carry;   // == cnt
    }
    __syncthreads();

    for (int i = t; i < cnt; i += 256) {
        unsigned v = sin[i];
        int b = v >> 24;                 // dst >> 8
        int pos = excl[b] + atomicAdd(&cur[b], 1);   // LDS atomic (fast)
        sout[pos] = v;
    }
    __syncthreads();

    for (int i = t; i < cnt; i += 256) packed[(size_t)e0 + i] = sout[i];   // coalesced
    for (int i = t; i <= NBK; i += 256) segdesc[(size_t)blockIdx.x * SDS + i] = (unsigned short)excl[i];
}

// ---------------- pass 2: per-bucket exact CSR (rpB/rpE/dinv/eidx), all in LDS ----------------

__launch_bounds__(256)
__global__ void k_p2(const unsigned* __restrict__ packed, const unsigned short* __restrict__ segdesc,
                     int NB1, unsigned short* __restrict__ eidx,
                     int* __restrict__ rpB, int* __restrict__ rpE,
                     float* __restrict__ dinv, int N) {
    __shared__ unsigned ev[BCAP];
    __shared__ unsigned short se[BCAP];
    __shared__ int lenS[512], offS[513];
    __shared__ int hist[NBINS], cur[NBINS], excl[NBINS + 1];
    const int t = threadIdx.x;
    const int b = blockIdx.x;

    if (t < NBINS) { hist[t] = 0; cur[t] = 0; }
    for (int blk = t; blk < NB1; blk += 256) {
        int s0 = segdesc[(size_t)blk * SDS + b];
        int s1 = segdesc[(size_t)blk * SDS + b + 1];
        lenS[blk] = s1 - s0;
    }
    __syncthreads();

    if (t < 64) {  // wave 0: exclusive scan of lenS[0..NB1)
        int carry = 0;
        for (int c = 0; c * 64 < NB1; ++c) {
            int idx = c * 64 + t;
            int v = (idx < NB1) ? lenS[idx] : 0;
            int x = v;
#pragma unroll
            for (int d = 1; d < 64; d <<= 1) { int y = __shfl_up(x, d, 64); if (t >= d) x += y; }
            if (idx < NB1) offS[idx] = carry + x - v;
            carry += __shfl(x, 63, 64);
        }
        if (t == 0) offS[NB1 < 512 ? NB1 : 512] = carry;
    }
    __syncthreads();
    const int total = min(offS[NB1 < 512 ? NB1 : 512], BCAP);

    for (int blk = t; blk < NB1; blk += 256) {
        int s0 = segdesc[(size_t)blk * SDS + b];
        int l = lenS[blk], o = offS[blk];
        if (o + l > BCAP) l = max(0, BCAP - o);
        const unsigned* sp = packed + (size_t)blk * EPB + s0;
        for (int j = 0; j < l; ++j) ev[o + j] = sp[j];
    }
    __syncthreads();

    for (int i = t; i < total; i += 256) atomicAdd(&hist[(ev[i] >> 16) & 0xFF], 1);
    __syncthreads();

    if (t < 64) {  // wave 0: exclusive scan of hist[0..256)
        int carry = 0;
#pragma unroll
        for (int c = 0; c < 4; ++c) {
            int idx = c * 64 + t;
            int v = hist[idx];
            int x = v;
#pragma unroll
            for (int d = 1; d < 64; d <<= 1) { int y = __shfl_up(x, d, 64); if (t >= d) x += y; }
            excl[idx] = carry + x - v;
            carry += __shfl(x, 63, 64);
        }
        if (t == 0) excl[NBINS] = carry;
    }
    __syncthreads();

    if (t < NBINS) {
        int d = b * NBINS + t;
        if (d < N) {
            int c = hist[t];
            int base = b * BCAP + excl[t];
            rpB[d] = base;
            rpE[d] = base + c;
            dinv[d] = rsqrtf((float)(c + 1));   // +1 self-loop
        }
    }
    for (int i = t; i < total; i += 256) {
        unsigned v = ev[i];
        int l = (v >> 16) & 0xFF;
        int p = excl[l] + atomicAdd(&cur[l], 1);
        se[p] = (unsigned short)(v & 0xFFFF);
    }
    __syncthreads();
    for (int i = t; i < total; i += 256) eidx[(size_t)b * BCAP + i] = se[i];
}

// ---------------- GEMM1: m1p = (x @ W1) * dinv[row] ----------------

__launch_bounds__(256)
__global__ void k_gemm1(const float* __restrict__ x, const float* __restrict__ W1,
                        const float* __restrict__ dinv,
                        float* __restrict__ m1p, int N) {
    __shared__ float xtT[32][68];
    __shared__ float wt[32][64];
    const int t  = threadIdx.x;
    const int tx = t & 15;
    const int ty = t >> 4;
    const int row0 = blockIdx.x * 64;

    float acc[4][4];
#pragma unroll
    for (int i = 0; i < 4; i++)
#pragma unroll
        for (int j = 0; j < 4; j++) acc[i][j] = 0.f;

    for (int k0 = 0; k0 < F_IN; k0 += 32) {
        __syncthreads();
#pragma unroll
        for (int l = 0; l < 2; l++) {
            int f4 = t + l * 256;
            {
                int r = f4 >> 3, c = (f4 & 7) << 2;
                int row = row0 + r;
                float4 v = make_float4(0.f, 0.f, 0.f, 0.f);
                if (row < N) v = *reinterpret_cast<const float4*>(&x[(size_t)row * F_IN + k0 + c]);
                xtT[c + 0][r] = v.x; xtT[c + 1][r] = v.y; xtT[c + 2][r] = v.z; xtT[c + 3][r] = v.w;
            }
            {
                int r = f4 >> 4, c = (f4 & 15) << 2;
                float4 v = *reinterpret_cast<const float4*>(&W1[(k0 + r) * 64 + c]);
                wt[r][c] = v.x; wt[r][c + 1] = v.y; wt[r][c + 2] = v.z; wt[r][c + 3] = v.w;
            }
        }
        __syncthreads();
#pragma unroll
        for (int kk = 0; kk < 32; kk++) {
            float4 xv = *reinterpret_cast<const float4*>(&xtT[kk][ty << 2]);
            float4 wv = *reinterpret_cast<const float4*>(&wt[kk][tx << 2]);
            acc[0][0] += xv.x * wv.x; acc[0][1] += xv.x * wv.y; acc[0][2] += xv.x * wv.z; acc[0][3] += xv.x * wv.w;
            acc[1][0] += xv.y * wv.x; acc[1][1] += xv.y * wv.y; acc[1][2] += xv.y * wv.z; acc[1][3] += xv.y * wv.w;
            acc[2][0] += xv.z * wv.x; acc[2][1] += xv.z * wv.y; acc[2][2] += xv.z * wv.z; acc[2][3] += xv.z * wv.w;
            acc[3][0] += xv.w * wv.x; acc[3][1] += xv.w * wv.y; acc[3][2] += xv.w * wv.z; acc[3][3] += xv.w * wv.w;
        }
    }
#pragma unroll
    for (int i = 0; i < 4; i++) {
        int row = row0 + (ty << 2) + i;
        if (row < N) {
            float s = dinv[row];
            float4 v = make_float4(acc[i][0] * s, acc[i][1] * s, acc[i][2] * s, acc[i][3] * s);
            *reinterpret_cast<float4*>(&m1p[(size_t)row * 64 + (tx << 2)]) = v;
        }
    }
}

// ---------------- CSR gather, 64 features: one wave per node ----------------

__launch_bounds__(256)
__global__ void k_gather64(const int* __restrict__ rpB, const int* __restrict__ rpE,
                           const unsigned short* __restrict__ eidx,
                           const float* __restrict__ msg, float* __restrict__ acc, int N) {
    int w = blockIdx.x * 4 + (threadIdx.x >> 6);
    if (w >= N) return;
    int f = threadIdx.x & 63;
    int i = rpB[w], e = rpE[w];
    float a0 = msg[(size_t)w * 64 + f];   // self-loop message
    float a1 = 0.f, a2 = 0.f, a3 = 0.f;
    for (; i + 4 <= e; i += 4) {
        int s0 = eidx[i], s1 = eidx[i + 1], s2 = eidx[i + 2], s3 = eidx[i + 3];
        a0 += msg[(size_t)s0 * 64 + f];
        a1 += msg[(size_t)s1 * 64 + f];
        a2 += msg[(size_t)s2 * 64 + f];
        a3 += msg[(size_t)s3 * 64 + f];
    }
    for (; i < e; i++) a0 += msg[(size_t)eidx[i] * 64 + f];
    acc[(size_t)w * 64 + f] = (a0 + a1) + (a2 + a3);
}

// ---------------- CSR gather, 32 features (optional fused relu/bias/scale epilogue) ----------------

__launch_bounds__(256)
__global__ void k_gather32(const int* __restrict__ rpB, const int* __restrict__ rpE,
                           const unsigned short* __restrict__ eidx,
                           const float* __restrict__ msg, float* __restrict__ outp, int N,
                           const float* __restrict__ bias, const float* __restrict__ dinv) {
    int w = blockIdx.x * 8 + (threadIdx.x >> 5);
    if (w >= N) return;
    int f = threadIdx.x & 31;
    int i = rpB[w], e = rpE[w];
    float a0 = msg[(size_t)w * 32 + f];
    float a1 = 0.f, a2 = 0.f, a3 = 0.f;
    for (; i + 4 <= e; i += 4) {
        int s0 = eidx[i], s1 = eidx[i + 1], s2 = eidx[i + 2], s3 = eidx[i + 3];
        a0 += msg[(size_t)s0 * 32 + f];
        a1 += msg[(size_t)s1 * 32 + f];
        a2 += msg[(size_t)s2 * 32 + f];
        a3 += msg[(size_t)s3 * 32 + f];
    }
    for (; i < e; i++) a0 += msg[(size_t)eidx[i] * 32 + f];
    float r = (a0 + a1) + (a2 + a3);
    if (bias) {  // fused mid-layer: h' = relu(r*s + b) * s
        float s = dinv[w];
        r = fmaxf(r * s + bias[f], 0.f) * s;
    }
    outp[(size_t)w * 32 + f] = r;
}

// ---------------- layer2: h1 = relu(s*acc1 + b1); m2p = (h1@W2)*s ----------------

__launch_bounds__(256)
__global__ void k_layer2(const float* __restrict__ acc1, const float* __restrict__ W2,
                         const float* __restrict__ b1, const float* __restrict__ dinv,
                         float* __restrict__ m2p, int N) {
    __shared__ float h1t[64][64];
    __shared__ float w2t[64][32];
    const int t = threadIdx.x;
    const int row0 = blockIdx.x * 64;
#pragma unroll
    for (int i = 0; i < 16; i++) {
        int lin = i * 256 + t;
        int r = lin >> 6, c = lin & 63;
        int row = row0 + r;
        float v = 0.f;
        if (row < N) v = fmaxf(acc1[(size_t)row * 64 + c] * dinv[row] + b1[c], 0.f);
        h1t[r][c] = v;
    }
#pragma unroll
    for (int i = 0; i < 8; i++) {
        int lin = i * 256 + t;
        w2t[lin >> 5][lin & 31] = W2[lin];
    }
    __syncthreads();
    const int tx = t & 31, ty = t >> 5;
#pragma unroll
    for (int rr = 0; rr < 8; rr++) {
        int r = rr * 8 + ty;
        float a = 0.f;
#pragma unroll
        for (int k = 0; k < 64; k++) a += h1t[r][k] * w2t[k][tx];
        int row = row0 + r;
        if (row < N) m2p[(size_t)row * 32 + tx] = a * dinv[row];
    }
}

// ---------------- out: wave-per-2-rows GEMV, W3 in LDS, coalesced row stores ----------------
// out[row] = (dinv[row]*acc3[row]) @ W3 + b3; sigmoid on col 0.
// 1024 threads = 16 waves/block; W3 (32x385, 49.3 KB) staged once; no per-row barriers.
// Store pattern: col = lane + 64*c -> every store instruction is 64 consecutive dwords.

__launch_bounds__(1024)
__global__ void k_out(const float* __restrict__ acc3, const float* __restrict__ W3,
                      const float* __restrict__ b3, const float* __restrict__ dinv,
                      float* __restrict__ out, int N, int total_waves) {
    __shared__ float w3t[32 * 385];
    const int t = threadIdx.x;
    for (int i = t; i < 32 * 385; i += 1024) w3t[i] = W3[i];
    __syncthreads();

    const int lane = t & 63;
    const int wgid = blockIdx.x * 16 + (t >> 6);

    float bias[6];
#pragma unroll
    for (int c = 0; c < 6; c++) bias[c] = b3[lane + 64 * c];
    const float bias384 = b3[384];

    for (int r0 = wgid * 2; r0 < N; r0 += total_waves * 2) {
        const int r1 = r0 + 1;
        const bool has1 = (r1 < N);
        // g for both rows in one register: lanes 0-31 = row0 feats, lanes 32-63 = row1 feats
        float gv;
        if (lane < 32) gv = acc3[(size_t)r0 * 32 + lane] * dinv[r0];
        else           gv = has1 ? acc3[(size_t)r1 * 32 + (lane - 32)] * dinv[r1] : 0.f;

        float a0[6], a1[6];
#pragma unroll
        for (int c = 0; c < 6; c++) { a0[c] = bias[c]; a1[c] = bias[c]; }
        float a0x = bias384, a1x = bias384;

#pragma unroll 4
        for (int k = 0; k < 32; k++) {
            float g0 = __shfl(gv, k, 64);
            float g1 = __shfl(gv, 32 + k, 64);
            const float* wrow = &w3t[k * 385];
#pragma unroll
            for (int c = 0; c < 6; c++) {
                float w = wrow[lane + 64 * c];
                a0[c] += g0 * w;
                a1[c] += g1 * w;
            }
            float wx = wrow[384];   // uniform -> LDS broadcast
            a0x += g0 * wx;
            a1x += g1 * wx;
        }

        size_t ob0 = (size_t)r0 * 385;
        {
            float v = a0[0];
            if (lane == 0) v = 1.0f / (1.0f + expf(-v));
            out[ob0 + lane] = v;
        }
#pragma unroll
        for (int c = 1; c < 6; c++) out[ob0 + lane + 64 * c] = a0[c];
        if (lane == 0) out[ob0 + 384] = a0x;

        if (has1) {
            size_t ob1 = (size_t)r1 * 385;
            {
                float v = a1[0];
                if (lane == 0) v = 1.0f / (1.0f + expf(-v));
                out[ob1 + lane] = v;
            }
#pragma unroll
            for (int c = 1; c < 6; c++) out[ob1 + lane + 64 * c] = a1[c];
            if (lane == 0) out[ob1 + 384] = a1x;
        }
    }
}

extern "C" void kernel_launch(void* const* d_in, const int* in_sizes, int n_in,
                              void* d_out, int out_size, void* d_ws, size_t ws_size,
                              hipStream_t stream) {
    const float* x  = (const float*)d_in[0];
    const int*   ei = (const int*)d_in[1];
    const float* W1 = (const float*)d_in[2];
    const float* b1 = (const float*)d_in[3];
    const float* W2 = (const float*)d_in[4];
    const float* b2 = (const float*)d_in[5];
    const float* W3 = (const float*)d_in[6];
    const float* b3 = (const float*)d_in[7];
    float* out = (float*)d_out;

    const int N = in_sizes[0] / F_IN;   // 50000
    const int E = in_sizes[1] / 2;      // 1600000
    const int NB1 = (E + EPB - 1) / EPB;       // 391 pass-1 blocks
    const int NBK = (N + NBINS - 1) / NBINS;   // 196 coarse buckets

    float* ws   = (float*)d_ws;
    float* dinv = ws;
    float* bufA = ws + N;
    float* bufB = bufA + (size_t)64 * N;
    int*   rpB  = (int*)(bufB + (size_t)64 * N);
    int*   rpE  = rpB + N;
    unsigned short* eidx    = (unsigned short*)(rpE + N);
    unsigned short* segdesc = eidx + (size_t)NBK * BCAP;

    unsigned* packed = (unsigned*)bufA;   // E u32 <= 64N floats; dead after k_p2
    float* m1p  = bufA;   // [N,64]
    float* acc1 = bufB;   // [N,64]
    float* m2p  = bufA;   // [N,32]
    float* h2p  = bufB;   // [N,32]
    float* acc3 = bufA;   // [N,32]

    k_p1<<<NB1, 256, 0, stream>>>(ei, E, NBK, packed, segdesc);
    k_p2<<<NBK, 256, 0, stream>>>(packed, segdesc, NB1, eidx, rpB, rpE, dinv, N);

    k_gemm1   <<<(N + 63) / 64, 256, 0, stream>>>(x, W1, dinv, m1p, N);
    k_gather64<<<(N + 3) / 4, 256, 0, stream>>>(rpB, rpE, eidx, m1p, acc1, N);

    k_layer2  <<<(N + 63) / 64, 256, 0, stream>>>(acc1, W2, b1, dinv, m2p, N);
    k_gather32<<<(N + 7) / 8, 256, 0, stream>>>(rpB, rpE, eidx, m2p, h2p, N, b2, dinv);   // fused mid3

    k_gather32<<<(N + 7) / 8, 256, 0, stream>>>(rpB, rpE, eidx, h2p, acc3, N, nullptr, dinv);

    const int OUT_BLOCKS = 512;
    k_out<<<OUT_BLOCKS, 1024, 0, stream>>>(acc3, W3, b3, dinv, out, N, OUT_BLOCKS * 16);
}

// Round 6
// 228.339 us; speedup vs baseline: 1.5703x; 1.2860x over previous
//
#include <hip/hip_runtime.h>

#define F_IN  384
#define EPB   4096   // edges per block, pass 1
#define NBINS 256    // dsts per coarse bucket
#define BCAP  12288  // eidx region stride per bucket (avg 8163, huge safety margin)
#define SDS   208    // segdesc row stride (u16 entries), >= NBK+1

// bf16 helpers (RNE), no header-type dependence
__device__ __forceinline__ unsigned short f2bf(float f) {
    unsigned u = __float_as_uint(f);
    return (unsigned short)((u + 0x7FFFu + ((u >> 16) & 1u)) >> 16);
}
__device__ __forceinline__ float bflo(unsigned u) { return __uint_as_float(u << 16); }
__device__ __forceinline__ float bfhi(unsigned u) { return __uint_as_float(u & 0xFFFF0000u); }

// ---------------- pass 1: coarse bucket partition (dst>>8), atomic-free ----------------

__launch_bounds__(256)
__global__ void k_p1(const int* __restrict__ ei, int E, int NBK,
                     unsigned* __restrict__ packed, unsigned short* __restrict__ segdesc) {
    __shared__ unsigned sin[EPB];
    __shared__ unsigned sout[EPB];
    __shared__ int hist[257], cur[256], excl[257];
    const int t = threadIdx.x;
    const int e0 = blockIdx.x * EPB;
    const int cnt = min(EPB, E - e0);

    if (t < 256) { hist[t] = 0; cur[t] = 0; }
    if (t == 0) hist[256] = 0;
    __syncthreads();

    for (int i = t; i < cnt; i += 256) {
        int s = ei[e0 + i];
        int d = ei[E + e0 + i];
        sin[i] = ((unsigned)d << 16) | (unsigned)s;   // N < 65536 for both
        atomicAdd(&hist[d >> 8], 1);
    }
    __syncthreads();

    if (t < 64) {  // wave 0: exclusive scan of hist[0..NBK)
        int carry = 0;
        for (int c = 0; c * 64 < NBK; ++c) {
            int idx = c * 64 + t;
            int v = (idx < NBK) ? hist[idx] : 0;
            int x = v;
#pragma unroll
            for (int d = 1; d < 64; d <<= 1) { int y = __shfl_up(x, d, 64); if (t >= d) x += y; }
            if (idx < NBK) excl[idx] = carry + x - v;
            carry += __shfl(x, 63, 64);
        }
        if (t == 0) excl[NBK] = carry;   // == cnt
    }
    __syncthreads();

    for (int i = t; i < cnt; i += 256) {
        unsigned v = sin[i];
        int b = v >> 24;                 // dst >> 8
        int pos = excl[b] + atomicAdd(&cur[b], 1);   // LDS atomic (fast)
        sout[pos] = v;
    }
    __syncthreads();

    for (int i = t; i < cnt; i += 256) packed[(size_t)e0 + i] = sout[i];   // coalesced
    for (int i = t; i <= NBK; i += 256) segdesc[(size_t)blockIdx.x * SDS + i] = (unsigned short)excl[i];
}

// ---------------- pass 2: per-bucket exact CSR (rpB/rpE/dinv/eidx), all in LDS ----------------

__launch_bounds__(256)
__global__ void k_p2(const unsigned* __restrict__ packed, const unsigned short* __restrict__ segdesc,
                     int NB1, unsigned short* __restrict__ eidx,
                     int* __restrict__ rpB, int* __restrict__ rpE,
                     float* __restrict__ dinv, int N) {
    __shared__ unsigned ev[BCAP];
    __shared__ unsigned short se[BCAP];
    __shared__ int lenS[512], offS[513];
    __shared__ int hist[NBINS], cur[NBINS], excl[NBINS + 1];
    const int t = threadIdx.x;
    const int b = blockIdx.x;

    if (t < NBINS) { hist[t] = 0; cur[t] = 0; }
    for (int blk = t; blk < NB1; blk += 256) {
        int s0 = segdesc[(size_t)blk * SDS + b];
        int s1 = segdesc[(size_t)blk * SDS + b + 1];
        lenS[blk] = s1 - s0;
    }
    __syncthreads();

    if (t < 64) {  // wave 0: exclusive scan of lenS[0..NB1)
        int carry = 0;
        for (int c = 0; c * 64 < NB1; ++c) {
            int idx = c * 64 + t;
            int v = (idx < NB1) ? lenS[idx] : 0;
            int x = v;
#pragma unroll
            for (int d = 1; d < 64; d <<= 1) { int y = __shfl_up(x, d, 64); if (t >= d) x += y; }
            if (idx < NB1) offS[idx] = carry + x - v;
            carry += __shfl(x, 63, 64);
        }
        if (t == 0) offS[NB1 < 512 ? NB1 : 512] = carry;
    }
    __syncthreads();
    const int total = min(offS[NB1 < 512 ? NB1 : 512], BCAP);

    for (int blk = t; blk < NB1; blk += 256) {
        int s0 = segdesc[(size_t)blk * SDS + b];
        int l = lenS[blk], o = offS[blk];
        if (o + l > BCAP) l = max(0, BCAP - o);
        const unsigned* sp = packed + (size_t)blk * EPB + s0;
        for (int j = 0; j < l; ++j) ev[o + j] = sp[j];
    }
    __syncthreads();

    for (int i = t; i < total; i += 256) atomicAdd(&hist[(ev[i] >> 16) & 0xFF], 1);
    __syncthreads();

    if (t < 64) {  // wave 0: exclusive scan of hist[0..256)
        int carry = 0;
#pragma unroll
        for (int c = 0; c < 4; ++c) {
            int idx = c * 64 + t;
            int v = hist[idx];
            int x = v;
#pragma unroll
            for (int d = 1; d < 64; d <<= 1) { int y = __shfl_up(x, d, 64); if (t >= d) x += y; }
            excl[idx] = carry + x - v;
            carry += __shfl(x, 63, 64);
        }
        if (t == 0) excl[NBINS] = carry;
    }
    __syncthreads();

    if (t < NBINS) {
        int d = b * NBINS + t;
        if (d < N) {
            int c = hist[t];
            int base = b * BCAP + excl[t];
            rpB[d] = base;
            rpE[d] = base + c;
            dinv[d] = rsqrtf((float)(c + 1));   // +1 self-loop
        }
    }
    for (int i = t; i < total; i += 256) {
        unsigned v = ev[i];
        int l = (v >> 16) & 0xFF;
        int p = excl[l] + atomicAdd(&cur[l], 1);
        se[p] = (unsigned short)(v & 0xFFFF);
    }
    __syncthreads();
    for (int i = t; i < total; i += 256) eidx[(size_t)b * BCAP + i] = se[i];
}

// ---------------- GEMM1: m1p = bf16((x @ W1) * dinv[row]) ----------------

__launch_bounds__(256)
__global__ void k_gemm1(const float* __restrict__ x, const float* __restrict__ W1,
                        const float* __restrict__ dinv,
                        unsigned short* __restrict__ m1p, int N) {
    __shared__ float xtT[32][68];
    __shared__ float wt[32][64];
    const int t  = threadIdx.x;
    const int tx = t & 15;
    const int ty = t >> 4;
    const int row0 = blockIdx.x * 64;

    float acc[4][4];
#pragma unroll
    for (int i = 0; i < 4; i++)
#pragma unroll
        for (int j = 0; j < 4; j++) acc[i][j] = 0.f;

    for (int k0 = 0; k0 < F_IN; k0 += 32) {
        __syncthreads();
#pragma unroll
        for (int l = 0; l < 2; l++) {
            int f4 = t + l * 256;
            {
                int r = f4 >> 3, c = (f4 & 7) << 2;
                int row = row0 + r;
                float4 v = make_float4(0.f, 0.f, 0.f, 0.f);
                if (row < N) v = *reinterpret_cast<const float4*>(&x[(size_t)row * F_IN + k0 + c]);
                xtT[c + 0][r] = v.x; xtT[c + 1][r] = v.y; xtT[c + 2][r] = v.z; xtT[c + 3][r] = v.w;
            }
            {
                int r = f4 >> 4, c = (f4 & 15) << 2;
                float4 v = *reinterpret_cast<const float4*>(&W1[(k0 + r) * 64 + c]);
                wt[r][c] = v.x; wt[r][c + 1] = v.y; wt[r][c + 2] = v.z; wt[r][c + 3] = v.w;
            }
        }
        __syncthreads();
#pragma unroll
        for (int kk = 0; kk < 32; kk++) {
            float4 xv = *reinterpret_cast<const float4*>(&xtT[kk][ty << 2]);
            float4 wv = *reinterpret_cast<const float4*>(&wt[kk][tx << 2]);
            acc[0][0] += xv.x * wv.x; acc[0][1] += xv.x * wv.y; acc[0][2] += xv.x * wv.z; acc[0][3] += xv.x * wv.w;
            acc[1][0] += xv.y * wv.x; acc[1][1] += xv.y * wv.y; acc[1][2] += xv.y * wv.z; acc[1][3] += xv.y * wv.w;
            acc[2][0] += xv.z * wv.x; acc[2][1] += xv.z * wv.y; acc[2][2] += xv.z * wv.z; acc[2][3] += xv.z * wv.w;
            acc[3][0] += xv.w * wv.x; acc[3][1] += xv.w * wv.y; acc[3][2] += xv.w * wv.z; acc[3][3] += xv.w * wv.w;
        }
    }
#pragma unroll
    for (int i = 0; i < 4; i++) {
        int row = row0 + (ty << 2) + i;
        if (row < N) {
            float s = dinv[row];
            ushort4 v;
            v.x = f2bf(acc[i][0] * s); v.y = f2bf(acc[i][1] * s);
            v.z = f2bf(acc[i][2] * s); v.w = f2bf(acc[i][3] * s);
            *reinterpret_cast<ushort4*>(&m1p[(size_t)row * 64 + (tx << 2)]) = v;
        }
    }
}

// ---------------- CSR gather, 64 bf16 features: half-wave per node, uint loads ----------------

__launch_bounds__(256)
__global__ void k_gather64h(const int* __restrict__ rpB, const int* __restrict__ rpE,
                            const unsigned short* __restrict__ eidx,
                            const unsigned* __restrict__ msg,   // [N][32] packed bf16 pairs
                            float* __restrict__ acc, int N) {
    int w = blockIdx.x * 8 + (threadIdx.x >> 5);
    if (w >= N) return;
    int f = threadIdx.x & 31;
    int i = rpB[w], e = rpE[w];
    unsigned u = msg[(size_t)w * 32 + f];           // self-loop
    float l0 = bflo(u), h0 = bfhi(u);
    float l1 = 0.f, h1 = 0.f, l2 = 0.f, h2 = 0.f, l3 = 0.f, h3 = 0.f;
    for (; i + 4 <= e; i += 4) {
        unsigned u0 = msg[(size_t)eidx[i]     * 32 + f];
        unsigned u1 = msg[(size_t)eidx[i + 1] * 32 + f];
        unsigned u2 = msg[(size_t)eidx[i + 2] * 32 + f];
        unsigned u3 = msg[(size_t)eidx[i + 3] * 32 + f];
        l0 += bflo(u0); h0 += bfhi(u0);
        l1 += bflo(u1); h1 += bfhi(u1);
        l2 += bflo(u2); h2 += bfhi(u2);
        l3 += bflo(u3); h3 += bfhi(u3);
    }
    for (; i < e; i++) {
        unsigned u0 = msg[(size_t)eidx[i] * 32 + f];
        l0 += bflo(u0); h0 += bfhi(u0);
    }
    *reinterpret_cast<float2*>(&acc[(size_t)w * 64 + (f << 1)]) =
        make_float2((l0 + l1) + (l2 + l3), (h0 + h1) + (h2 + h3));
}

// ---------------- CSR gather, 32 bf16 features: 16 lanes per node, uint loads ----------------
// bias != null: fused mid-layer epilogue h' = bf16(relu(r*s + b) * s) packed to outp (uint rows)
// bias == null: write f32 float2 rows to outp

__launch_bounds__(256)
__global__ void k_gather32h(const int* __restrict__ rpB, const int* __restrict__ rpE,
                            const unsigned short* __restrict__ eidx,
                            const unsigned* __restrict__ msg,   // [N][16] packed bf16 pairs
                            void* __restrict__ outp, int N,
                            const float* __restrict__ bias, const float* __restrict__ dinv) {
    int w = blockIdx.x * 16 + (threadIdx.x >> 4);
    if (w >= N) return;
    int f = threadIdx.x & 15;
    int i = rpB[w], e = rpE[w];
    unsigned u = msg[(size_t)w * 16 + f];           // self-loop
    float l0 = bflo(u), h0 = bfhi(u);
    float l1 = 0.f, h1 = 0.f, l2 = 0.f, h2 = 0.f, l3 = 0.f, h3 = 0.f;
    for (; i + 4 <= e; i += 4) {
        unsigned u0 = msg[(size_t)eidx[i]     * 16 + f];
        unsigned u1 = msg[(size_t)eidx[i + 1] * 16 + f];
        unsigned u2 = msg[(size_t)eidx[i + 2] * 16 + f];
        unsigned u3 = msg[(size_t)eidx[i + 3] * 16 + f];
        l0 += bflo(u0); h0 += bfhi(u0);
        l1 += bflo(u1); h1 += bfhi(u1);
        l2 += bflo(u2); h2 += bfhi(u2);
        l3 += bflo(u3); h3 += bfhi(u3);
    }
    for (; i < e; i++) {
        unsigned u0 = msg[(size_t)eidx[i] * 16 + f];
        l0 += bflo(u0); h0 += bfhi(u0);
    }
    float rl = (l0 + l1) + (l2 + l3);
    float rh = (h0 + h1) + (h2 + h3);
    if (bias) {
        float s = dinv[w];
        rl = fmaxf(rl * s + bias[(f << 1)], 0.f) * s;
        rh = fmaxf(rh * s + bias[(f << 1) + 1], 0.f) * s;
        ((unsigned*)outp)[(size_t)w * 16 + f] = (unsigned)f2bf(rl) | ((unsigned)f2bf(rh) << 16);
    } else {
        ((float2*)outp)[(size_t)w * 16 + f] = make_float2(rl, rh);
    }
}

// ---------------- layer2: h1 = relu(s*acc1 + b1); m2p = bf16((h1@W2)*s) ----------------

__launch_bounds__(256)
__global__ void k_layer2(const float* __restrict__ acc1, const float* __restrict__ W2,
                         const float* __restrict__ b1, const float* __restrict__ dinv,
                         unsigned short* __restrict__ m2p, int N) {
    __shared__ float h1t[64][64];
    __shared__ float w2t[64][32];
    const int t = threadIdx.x;
    const int row0 = blockIdx.x * 64;
#pragma unroll
    for (int i = 0; i < 16; i++) {
        int lin = i * 256 + t;
        int r = lin >> 6, c = lin & 63;
        int row = row0 + r;
        float v = 0.f;
        if (row < N) v = fmaxf(acc1[(size_t)row * 64 + c] * dinv[row] + b1[c], 0.f);
        h1t[r][c] = v;
    }
#pragma unroll
    for (int i = 0; i < 8; i++) {
        int lin = i * 256 + t;
        w2t[lin >> 5][lin & 31] = W2[lin];
    }
    __syncthreads();
    const int tx = t & 31, ty = t >> 5;
#pragma unroll
    for (int rr = 0; rr < 8; rr++) {
        int r = rr * 8 + ty;
        float a = 0.f;
#pragma unroll
        for (int k = 0; k < 64; k++) a += h1t[r][k] * w2t[k][tx];
        int row = row0 + r;
        if (row < N) m2p[(size_t)row * 32 + tx] = f2bf(a * dinv[row]);
    }
}

// ---------------- out: wave-per-2-rows GEMV, W3 in LDS, coalesced row stores ----------------

__launch_bounds__(1024)
__global__ void k_out(const float* __restrict__ acc3, const float* __restrict__ W3,
                      const float* __restrict__ b3, const float* __restrict__ dinv,
                      float* __restrict__ out, int N, int total_waves) {
    __shared__ float w3t[32 * 385];
    const int t = threadIdx.x;
    for (int i = t; i < 32 * 385; i += 1024) w3t[i] = W3[i];
    __syncthreads();

    const int lane = t & 63;
    const int wgid = blockIdx.x * 16 + (t >> 6);

    float bias[6];
#pragma unroll
    for (int c = 0; c < 6; c++) bias[c] = b3[lane + 64 * c];
    const float bias384 = b3[384];

    for (int r0 = wgid * 2; r0 < N; r0 += total_waves * 2) {
        const int r1 = r0 + 1;
        const bool has1 = (r1 < N);
        float gv;
        if (lane < 32) gv = acc3[(size_t)r0 * 32 + lane] * dinv[r0];
        else           gv = has1 ? acc3[(size_t)r1 * 32 + (lane - 32)] * dinv[r1] : 0.f;

        float a0[6], a1[6];
#pragma unroll
        for (int c = 0; c < 6; c++) { a0[c] = bias[c]; a1[c] = bias[c]; }
        float a0x = bias384, a1x = bias384;

#pragma unroll 4
        for (int k = 0; k < 32; k++) {
            float g0 = __shfl(gv, k, 64);
            float g1 = __shfl(gv, 32 + k, 64);
            const float* wrow = &w3t[k * 385];
#pragma unroll
            for (int c = 0; c < 6; c++) {
                float w = wrow[lane + 64 * c];
                a0[c] += g0 * w;
                a1[c] += g1 * w;
            }
            float wx = wrow[384];
            a0x += g0 * wx;
            a1x += g1 * wx;
        }

        size_t ob0 = (size_t)r0 * 385;
        {
            float v = a0[0];
            if (lane == 0) v = 1.0f / (1.0f + expf(-v));
            out[ob0 + lane] = v;
        }
#pragma unroll
        for (int c = 1; c < 6; c++) out[ob0 + lane + 64 * c] = a0[c];
        if (lane == 0) out[ob0 + 384] = a0x;

        if (has1) {
            size_t ob1 = (size_t)r1 * 385;
            {
                float v = a1[0];
                if (lane == 0) v = 1.0f / (1.0f + expf(-v));
                out[ob1 + lane] = v;
            }
#pragma unroll
            for (int c = 1; c < 6; c++) out[ob1 + lane + 64 * c] = a1[c];
            if (lane == 0) out[ob1 + 384] = a1x;
        }
    }
}

extern "C" void kernel_launch(void* const* d_in, const int* in_sizes, int n_in,
                              void* d_out, int out_size, void* d_ws, size_t ws_size,
                              hipStream_t stream) {
    const float* x  = (const float*)d_in[0];
    const int*   ei = (const int*)d_in[1];
    const float* W1 = (const float*)d_in[2];
    const float* b1 = (const float*)d_in[3];
    const float* W2 = (const float*)d_in[4];
    const float* b2 = (const float*)d_in[5];
    const float* W3 = (const float*)d_in[6];
    const float* b3 = (const float*)d_in[7];
    float* out = (float*)d_out;

    const int N = in_sizes[0] / F_IN;   // 50000
    const int E = in_sizes[1] / 2;      // 1600000
    const int NB1 = (E + EPB - 1) / EPB;       // 391 pass-1 blocks
    const int NBK = (N + NBINS - 1) / NBINS;   // 196 coarse buckets

    float* ws   = (float*)d_ws;
    float* dinv = ws;
    float* bufA = ws + N;
    float* bufB = bufA + (size_t)64 * N;
    int*   rpB  = (int*)(bufB + (size_t)64 * N);
    int*   rpE  = rpB + N;
    unsigned short* eidx    = (unsigned short*)(rpE + N);
    unsigned short* segdesc = eidx + (size_t)NBK * BCAP;

    unsigned* packed = (unsigned*)bufA;              // E u32; dead after k_p2
    unsigned short* m1p = (unsigned short*)bufA;     // [N,64] bf16 (6.4 MB)
    float* acc1 = bufB;                              // [N,64] f32
    unsigned short* m2p = (unsigned short*)bufA;     // [N,32] bf16
    unsigned short* h2p = (unsigned short*)bufB;     // [N,32] bf16 (acc1 dead)
    float* acc3 = bufA + (size_t)32 * N;             // [N,32] f32 (distinct from h2p's buffer)

    k_p1<<<NB1, 256, 0, stream>>>(ei, E, NBK, packed, segdesc);
    k_p2<<<NBK, 256, 0, stream>>>(packed, segdesc, NB1, eidx, rpB, rpE, dinv, N);

    k_gemm1    <<<(N + 63) / 64, 256, 0, stream>>>(x, W1, dinv, m1p, N);
    k_gather64h<<<(N + 7) / 8, 256, 0, stream>>>(rpB, rpE, eidx, (const unsigned*)m1p, acc1, N);

    k_layer2   <<<(N + 63) / 64, 256, 0, stream>>>(acc1, W2, b1, dinv, m2p, N);
    k_gather32h<<<(N + 15) / 16, 256, 0, stream>>>(rpB, rpE, eidx, (const unsigned*)m2p,
                                                   (void*)h2p, N, b2, dinv);   // fused mid3, bf16 out

    k_gather32h<<<(N + 15) / 16, 256, 0, stream>>>(rpB, rpE, eidx, (const unsigned*)h2p,
                                                   (void*)acc3, N, nullptr, dinv);

    const int OUT_BLOCKS = 512;
    k_out<<<OUT_BLOCKS, 1024, 0, stream>>>(acc3, W3, b3, dinv, out, N, OUT_BLOCKS * 16);
}

// Round 7
// 217.575 us; speedup vs baseline: 1.6480x; 1.0495x over previous
//
#include <hip/hip_runtime.h>

#define F_IN  384
#define EPB   4096   // edges per block, pass 1
#define NBINS 256    // dsts per coarse bucket
#define BCAP  12288  // eidx region stride per bucket (avg 8163, huge safety margin)
#define SDS   208    // segdesc row stride (u16 entries), >= NBK+1

// bf16 helpers (RNE), no header-type dependence
__device__ __forceinline__ unsigned short f2bf(float f) {
    unsigned u = __float_as_uint(f);
    return (unsigned short)((u + 0x7FFFu + ((u >> 16) & 1u)) >> 16);
}
__device__ __forceinline__ float bflo(unsigned u) { return __uint_as_float(u << 16); }
__device__ __forceinline__ float bfhi(unsigned u) { return __uint_as_float(u & 0xFFFF0000u); }

// ---------------- pass 1: coarse bucket partition (dst>>8), atomic-free ----------------

__launch_bounds__(256)
__global__ void k_p1(const int* __restrict__ ei, int E, int NBK,
                     unsigned* __restrict__ packed, unsigned short* __restrict__ segdesc) {
    __shared__ unsigned sin[EPB];
    __shared__ unsigned sout[EPB];
    __shared__ int hist[257], cur[256], excl[257];
    const int t = threadIdx.x;
    const int e0 = blockIdx.x * EPB;
    const int cnt = min(EPB, E - e0);

    if (t < 256) { hist[t] = 0; cur[t] = 0; }
    if (t == 0) hist[256] = 0;
    __syncthreads();

    for (int i = t; i < cnt; i += 256) {
        int s = ei[e0 + i];
        int d = ei[E + e0 + i];
        sin[i] = ((unsigned)d << 16) | (unsigned)s;   // N < 65536 for both
        atomicAdd(&hist[d >> 8], 1);
    }
    __syncthreads();

    if (t < 64) {  // wave 0: exclusive scan of hist[0..NBK)
        int carry = 0;
        for (int c = 0; c * 64 < NBK; ++c) {
            int idx = c * 64 + t;
            int v = (idx < NBK) ? hist[idx] : 0;
            int x = v;
#pragma unroll
            for (int d = 1; d < 64; d <<= 1) { int y = __shfl_up(x, d, 64); if (t >= d) x += y; }
            if (idx < NBK) excl[idx] = carry + x - v;
            carry += __shfl(x, 63, 64);
        }
        if (t == 0) excl[NBK] = carry;   // == cnt
    }
    __syncthreads();

    for (int i = t; i < cnt; i += 256) {
        unsigned v = sin[i];
        int b = v >> 24;                 // dst >> 8
        int pos = excl[b] + atomicAdd(&cur[b], 1);   // LDS atomic (fast)
        sout[pos] = v;
    }
    __syncthreads();

    for (int i = t; i < cnt; i += 256) packed[(size_t)e0 + i] = sout[i];   // coalesced
    for (int i = t; i <= NBK; i += 256) segdesc[(size_t)blockIdx.x * SDS + i] = (unsigned short)excl[i];
}

// ---------------- pass 2: per-bucket exact CSR (rpB/rpE/dinv/eidx), all in LDS ----------------

__launch_bounds__(256)
__global__ void k_p2(const unsigned* __restrict__ packed, const unsigned short* __restrict__ segdesc,
                     int NB1, unsigned short* __restrict__ eidx,
                     int* __restrict__ rpB, int* __restrict__ rpE,
                     float* __restrict__ dinv, int N) {
    __shared__ unsigned ev[BCAP];
    __shared__ unsigned short se[BCAP];
    __shared__ int lenS[512], offS[513];
    __shared__ int hist[NBINS], cur[NBINS], excl[NBINS + 1];
    const int t = threadIdx.x;
    const int b = blockIdx.x;

    if (t < NBINS) { hist[t] = 0; cur[t] = 0; }
    for (int blk = t; blk < NB1; blk += 256) {
        int s0 = segdesc[(size_t)blk * SDS + b];
        int s1 = segdesc[(size_t)blk * SDS + b + 1];
        lenS[blk] = s1 - s0;
    }
    __syncthreads();

    if (t < 64) {  // wave 0: exclusive scan of lenS[0..NB1)
        int carry = 0;
        for (int c = 0; c * 64 < NB1; ++c) {
            int idx = c * 64 + t;
            int v = (idx < NB1) ? lenS[idx] : 0;
            int x = v;
#pragma unroll
            for (int d = 1; d < 64; d <<= 1) { int y = __shfl_up(x, d, 64); if (t >= d) x += y; }
            if (idx < NB1) offS[idx] = carry + x - v;
            carry += __shfl(x, 63, 64);
        }
        if (t == 0) offS[NB1 < 512 ? NB1 : 512] = carry;
    }
    __syncthreads();
    const int total = min(offS[NB1 < 512 ? NB1 : 512], BCAP);

    for (int blk = t; blk < NB1; blk += 256) {
        int s0 = segdesc[(size_t)blk * SDS + b];
        int l = lenS[blk], o = offS[blk];
        if (o + l > BCAP) l = max(0, BCAP - o);
        const unsigned* sp = packed + (size_t)blk * EPB + s0;
        for (int j = 0; j < l; ++j) ev[o + j] = sp[j];
    }
    __syncthreads();

    for (int i = t; i < total; i += 256) atomicAdd(&hist[(ev[i] >> 16) & 0xFF], 1);
    __syncthreads();

    if (t < 64) {  // wave 0: exclusive scan of hist[0..256)
        int carry = 0;
#pragma unroll
        for (int c = 0; c < 4; ++c) {
            int idx = c * 64 + t;
            int v = hist[idx];
            int x = v;
#pragma unroll
            for (int d = 1; d < 64; d <<= 1) { int y = __shfl_up(x, d, 64); if (t >= d) x += y; }
            excl[idx] = carry + x - v;
            carry += __shfl(x, 63, 64);
        }
        if (t == 0) excl[NBINS] = carry;
    }
    __syncthreads();

    if (t < NBINS) {
        int d = b * NBINS + t;
        if (d < N) {
            int c = hist[t];
            int base = b * BCAP + excl[t];
            rpB[d] = base;
            rpE[d] = base + c;
            dinv[d] = rsqrtf((float)(c + 1));   // +1 self-loop
        }
    }
    for (int i = t; i < total; i += 256) {
        unsigned v = ev[i];
        int l = (v >> 16) & 0xFF;
        int p = excl[l] + atomicAdd(&cur[l], 1);
        se[p] = (unsigned short)(v & 0xFFFF);
    }
    __syncthreads();
    for (int i = t; i < total; i += 256) eidx[(size_t)b * BCAP + i] = se[i];
}

// ---------------- GEMM1: m1p = bf16((x @ W1) * dinv[row]) ----------------

__launch_bounds__(256)
__global__ void k_gemm1(const float* __restrict__ x, const float* __restrict__ W1,
                        const float* __restrict__ dinv,
                        unsigned short* __restrict__ m1p, int N) {
    __shared__ float xtT[32][68];
    __shared__ float wt[32][64];
    const int t  = threadIdx.x;
    const int tx = t & 15;
    const int ty = t >> 4;
    const int row0 = blockIdx.x * 64;

    float acc[4][4];
#pragma unroll
    for (int i = 0; i < 4; i++)
#pragma unroll
        for (int j = 0; j < 4; j++) acc[i][j] = 0.f;

    for (int k0 = 0; k0 < F_IN; k0 += 32) {
        __syncthreads();
#pragma unroll
        for (int l = 0; l < 2; l++) {
            int f4 = t + l * 256;
            {
                int r = f4 >> 3, c = (f4 & 7) << 2;
                int row = row0 + r;
                float4 v = make_float4(0.f, 0.f, 0.f, 0.f);
                if (row < N) v = *reinterpret_cast<const float4*>(&x[(size_t)row * F_IN + k0 + c]);
                xtT[c + 0][r] = v.x; xtT[c + 1][r] = v.y; xtT[c + 2][r] = v.z; xtT[c + 3][r] = v.w;
            }
            {
                int r = f4 >> 4, c = (f4 & 15) << 2;
                float4 v = *reinterpret_cast<const float4*>(&W1[(k0 + r) * 64 + c]);
                wt[r][c] = v.x; wt[r][c + 1] = v.y; wt[r][c + 2] = v.z; wt[r][c + 3] = v.w;
            }
        }
        __syncthreads();
#pragma unroll
        for (int kk = 0; kk < 32; kk++) {
            float4 xv = *reinterpret_cast<const float4*>(&xtT[kk][ty << 2]);
            float4 wv = *reinterpret_cast<const float4*>(&wt[kk][tx << 2]);
            acc[0][0] += xv.x * wv.x; acc[0][1] += xv.x * wv.y; acc[0][2] += xv.x * wv.z; acc[0][3] += xv.x * wv.w;
            acc[1][0] += xv.y * wv.x; acc[1][1] += xv.y * wv.y; acc[1][2] += xv.y * wv.z; acc[1][3] += xv.y * wv.w;
            acc[2][0] += xv.z * wv.x; acc[2][1] += xv.z * wv.y; acc[2][2] += xv.z * wv.z; acc[2][3] += xv.z * wv.w;
            acc[3][0] += xv.w * wv.x; acc[3][1] += xv.w * wv.y; acc[3][2] += xv.w * wv.z; acc[3][3] += xv.w * wv.w;
        }
    }
#pragma unroll
    for (int i = 0; i < 4; i++) {
        int row = row0 + (ty << 2) + i;
        if (row < N) {
            float s = dinv[row];
            ushort4 v;
            v.x = f2bf(acc[i][0] * s); v.y = f2bf(acc[i][1] * s);
            v.z = f2bf(acc[i][2] * s); v.w = f2bf(acc[i][3] * s);
            *reinterpret_cast<ushort4*>(&m1p[(size_t)row * 64 + (tx << 2)]) = v;
        }
    }
}

// ---------------- CSR gather, 64 bf16 features: half-wave per node, uint loads ----------------

__launch_bounds__(256)
__global__ void k_gather64h(const int* __restrict__ rpB, const int* __restrict__ rpE,
                            const unsigned short* __restrict__ eidx,
                            const unsigned* __restrict__ msg,   // [N][32] packed bf16 pairs
                            float* __restrict__ acc, int N) {
    int w = blockIdx.x * 8 + (threadIdx.x >> 5);
    if (w >= N) return;
    int f = threadIdx.x & 31;
    int i = rpB[w], e = rpE[w];
    unsigned u = msg[(size_t)w * 32 + f];           // self-loop
    float l0 = bflo(u), h0 = bfhi(u);
    float l1 = 0.f, h1 = 0.f, l2 = 0.f, h2 = 0.f, l3 = 0.f, h3 = 0.f;
    for (; i + 4 <= e; i += 4) {
        unsigned u0 = msg[(size_t)eidx[i]     * 32 + f];
        unsigned u1 = msg[(size_t)eidx[i + 1] * 32 + f];
        unsigned u2 = msg[(size_t)eidx[i + 2] * 32 + f];
        unsigned u3 = msg[(size_t)eidx[i + 3] * 32 + f];
        l0 += bflo(u0); h0 += bfhi(u0);
        l1 += bflo(u1); h1 += bfhi(u1);
        l2 += bflo(u2); h2 += bfhi(u2);
        l3 += bflo(u3); h3 += bfhi(u3);
    }
    for (; i < e; i++) {
        unsigned u0 = msg[(size_t)eidx[i] * 32 + f];
        l0 += bflo(u0); h0 += bfhi(u0);
    }
    *reinterpret_cast<float2*>(&acc[(size_t)w * 64 + (f << 1)]) =
        make_float2((l0 + l1) + (l2 + l3), (h0 + h1) + (h2 + h3));
}

// ---------------- CSR gather, 32 bf16 features: 16 lanes per node, uint loads ----------------

__launch_bounds__(256)
__global__ void k_gather32h(const int* __restrict__ rpB, const int* __restrict__ rpE,
                            const unsigned short* __restrict__ eidx,
                            const unsigned* __restrict__ msg,   // [N][16] packed bf16 pairs
                            void* __restrict__ outp, int N,
                            const float* __restrict__ bias, const float* __restrict__ dinv) {
    int w = blockIdx.x * 16 + (threadIdx.x >> 4);
    if (w >= N) return;
    int f = threadIdx.x & 15;
    int i = rpB[w], e = rpE[w];
    unsigned u = msg[(size_t)w * 16 + f];           // self-loop
    float l0 = bflo(u), h0 = bfhi(u);
    float l1 = 0.f, h1 = 0.f, l2 = 0.f, h2 = 0.f, l3 = 0.f, h3 = 0.f;
    for (; i + 4 <= e; i += 4) {
        unsigned u0 = msg[(size_t)eidx[i]     * 16 + f];
        unsigned u1 = msg[(size_t)eidx[i + 1] * 16 + f];
        unsigned u2 = msg[(size_t)eidx[i + 2] * 16 + f];
        unsigned u3 = msg[(size_t)eidx[i + 3] * 16 + f];
        l0 += bflo(u0); h0 += bfhi(u0);
        l1 += bflo(u1); h1 += bfhi(u1);
        l2 += bflo(u2); h2 += bfhi(u2);
        l3 += bflo(u3); h3 += bfhi(u3);
    }
    for (; i < e; i++) {
        unsigned u0 = msg[(size_t)eidx[i] * 16 + f];
        l0 += bflo(u0); h0 += bfhi(u0);
    }
    float rl = (l0 + l1) + (l2 + l3);
    float rh = (h0 + h1) + (h2 + h3);
    if (bias) {
        float s = dinv[w];
        rl = fmaxf(rl * s + bias[(f << 1)], 0.f) * s;
        rh = fmaxf(rh * s + bias[(f << 1) + 1], 0.f) * s;
        ((unsigned*)outp)[(size_t)w * 16 + f] = (unsigned)f2bf(rl) | ((unsigned)f2bf(rh) << 16);
    } else {
        ((float2*)outp)[(size_t)w * 16 + f] = make_float2(rl, rh);
    }
}

// ---------------- layer2: h1 = relu(s*acc1 + b1); m2p = bf16((h1@W2)*s) ----------------

__launch_bounds__(256)
__global__ void k_layer2(const float* __restrict__ acc1, const float* __restrict__ W2,
                         const float* __restrict__ b1, const float* __restrict__ dinv,
                         unsigned short* __restrict__ m2p, int N) {
    __shared__ float h1t[64][64];
    __shared__ float w2t[64][32];
    const int t = threadIdx.x;
    const int row0 = blockIdx.x * 64;
#pragma unroll
    for (int i = 0; i < 16; i++) {
        int lin = i * 256 + t;
        int r = lin >> 6, c = lin & 63;
        int row = row0 + r;
        float v = 0.f;
        if (row < N) v = fmaxf(acc1[(size_t)row * 64 + c] * dinv[row] + b1[c], 0.f);
        h1t[r][c] = v;
    }
#pragma unroll
    for (int i = 0; i < 8; i++) {
        int lin = i * 256 + t;
        w2t[lin >> 5][lin & 31] = W2[lin];
    }
    __syncthreads();
    const int tx = t & 31, ty = t >> 5;
#pragma unroll
    for (int rr = 0; rr < 8; rr++) {
        int r = rr * 8 + ty;
        float a = 0.f;
#pragma unroll
        for (int k = 0; k < 64; k++) a += h1t[r][k] * w2t[k][tx];
        int row = row0 + r;
        if (row < N) m2p[(size_t)row * 32 + tx] = f2bf(a * dinv[row]);
    }
}

// ---------------- out: wave-per-8-rows GEMV, W3 in LDS, coalesced row stores ----------------
// out[row] = (dinv[row]*acc3[row]) @ W3 + b3; sigmoid on col 0.
// 512 threads = 8 waves; W3 staged once; each wave does 8 rows per pass so the
// 6 w-reads + 1 broadcast per k are amortized 8x (DS ~3.8 clk/row vs 9 before).

__launch_bounds__(512, 5)
__global__ void k_out(const float* __restrict__ acc3, const float* __restrict__ W3,
                      const float* __restrict__ b3, const float* __restrict__ dinv,
                      float* __restrict__ out, int N, int total_waves) {
    __shared__ float w3t[32 * 385];
    const int t = threadIdx.x;
    for (int i = t; i < 32 * 385; i += 512) w3t[i] = W3[i];
    __syncthreads();

    const int lane = t & 63;
    const int wv = blockIdx.x * 8 + (t >> 6);
    const int half = lane >> 5;        // 0 or 1
    const int feat = lane & 31;

    float bias[6];
#pragma unroll
    for (int c = 0; c < 6; c++) bias[c] = b3[lane + 64 * c];
    const float bias384 = b3[384];

    for (int r0 = wv * 8; r0 < N; r0 += total_waves * 8) {
        // gv[j]: lane holds g[row r0+2j+half][feat]
        float gv[4];
#pragma unroll
        for (int j = 0; j < 4; j++) {
            int r = r0 + 2 * j + half;
            gv[j] = (r < N) ? acc3[(size_t)r * 32 + feat] * dinv[r] : 0.f;
        }

        float a[8][6], ax[8];
#pragma unroll
        for (int r = 0; r < 8; r++) {
#pragma unroll
            for (int c = 0; c < 6; c++) a[r][c] = bias[c];
            ax[r] = bias384;
        }

#pragma unroll 2
        for (int k = 0; k < 32; k++) {
            float g[8];
#pragma unroll
            for (int j = 0; j < 4; j++) {
                g[2 * j]     = __shfl(gv[j], k, 64);
                g[2 * j + 1] = __shfl(gv[j], 32 + k, 64);
            }
            const float* wrow = &w3t[k * 385];
            float w[6];
#pragma unroll
            for (int c = 0; c < 6; c++) w[c] = wrow[lane + 64 * c];
            float wx = wrow[384];   // uniform -> LDS broadcast
#pragma unroll
            for (int r = 0; r < 8; r++) {
#pragma unroll
                for (int c = 0; c < 6; c++) a[r][c] += g[r] * w[c];
                ax[r] += g[r] * wx;
            }
        }

#pragma unroll
        for (int r = 0; r < 8; r++) {
            int row = r0 + r;
            if (row < N) {
                size_t ob = (size_t)row * 385;
                float v0 = a[r][0];
                if (lane == 0) v0 = 1.0f / (1.0f + expf(-v0));
                out[ob + lane] = v0;
#pragma unroll
                for (int c = 1; c < 6; c++) out[ob + lane + 64 * c] = a[r][c];
                if (lane == 0) out[ob + 384] = ax[r];
            }
        }
    }
}

extern "C" void kernel_launch(void* const* d_in, const int* in_sizes, int n_in,
                              void* d_out, int out_size, void* d_ws, size_t ws_size,
                              hipStream_t stream) {
    const float* x  = (const float*)d_in[0];
    const int*   ei = (const int*)d_in[1];
    const float* W1 = (const float*)d_in[2];
    const float* b1 = (const float*)d_in[3];
    const float* W2 = (const float*)d_in[4];
    const float* b2 = (const float*)d_in[5];
    const float* W3 = (const float*)d_in[6];
    const float* b3 = (const float*)d_in[7];
    float* out = (float*)d_out;

    const int N = in_sizes[0] / F_IN;   // 50000
    const int E = in_sizes[1] / 2;      // 1600000
    const int NB1 = (E + EPB - 1) / EPB;       // 391 pass-1 blocks
    const int NBK = (N + NBINS - 1) / NBINS;   // 196 coarse buckets

    float* ws   = (float*)d_ws;
    float* dinv = ws;
    float* bufA = ws + N;
    float* bufB = bufA + (size_t)64 * N;
    int*   rpB  = (int*)(bufB + (size_t)64 * N);
    int*   rpE  = rpB + N;
    unsigned short* eidx    = (unsigned short*)(rpE + N);
    unsigned short* segdesc = eidx + (size_t)NBK * BCAP;

    unsigned* packed = (unsigned*)bufA;              // E u32; dead after k_p2
    unsigned short* m1p = (unsigned short*)bufA;     // [N,64] bf16 (6.4 MB)
    float* acc1 = bufB;                              // [N,64] f32
    unsigned short* m2p = (unsigned short*)bufA;     // [N,32] bf16
    unsigned short* h2p = (unsigned short*)bufB;     // [N,32] bf16 (acc1 dead)
    float* acc3 = bufA + (size_t)32 * N;             // [N,32] f32 (distinct from m2p region)

    k_p1<<<NB1, 256, 0, stream>>>(ei, E, NBK, packed, segdesc);
    k_p2<<<NBK, 256, 0, stream>>>(packed, segdesc, NB1, eidx, rpB, rpE, dinv, N);

    k_gemm1    <<<(N + 63) / 64, 256, 0, stream>>>(x, W1, dinv, m1p, N);
    k_gather64h<<<(N + 7) / 8, 256, 0, stream>>>(rpB, rpE, eidx, (const unsigned*)m1p, acc1, N);

    k_layer2   <<<(N + 63) / 64, 256, 0, stream>>>(acc1, W2, b1, dinv, m2p, N);
    k_gather32h<<<(N + 15) / 16, 256, 0, stream>>>(rpB, rpE, eidx, (const unsigned*)m2p,
                                                   (void*)h2p, N, b2, dinv);   // fused mid3, bf16 out

    k_gather32h<<<(N + 15) / 16, 256, 0, stream>>>(rpB, rpE, eidx, (const unsigned*)h2p,
                                                   (void*)acc3, N, nullptr, dinv);

    const int OUT_BLOCKS = 512;
    k_out<<<OUT_BLOCKS, 512, 0, stream>>>(acc3, W3, b3, dinv, out, N, OUT_BLOCKS * 8);
}

// Round 8
// 196.710 us; speedup vs baseline: 1.8228x; 1.1061x over previous
//
#include <hip/hip_runtime.h>

#define F_IN  384
#define EPB   4096   // edges per block, pass 1
#define NBINS 256    // dsts per coarse bucket
#define BCAP  12288  // eidx region stride per bucket (avg 8163, huge safety margin)
#define SDS   208    // segdesc row stride (u16 entries), >= NBK+1

typedef __attribute__((ext_vector_type(8))) short short8v;   // bf16x8 MFMA fragment
typedef __attribute__((ext_vector_type(4))) float f32x4;     // MFMA accumulator

// bf16 helpers (RNE), no header-type dependence
__device__ __forceinline__ unsigned short f2bf(float f) {
    unsigned u = __float_as_uint(f);
    return (unsigned short)((u + 0x7FFFu + ((u >> 16) & 1u)) >> 16);
}
__device__ __forceinline__ float bflo(unsigned u) { return __uint_as_float(u << 16); }
__device__ __forceinline__ float bfhi(unsigned u) { return __uint_as_float(u & 0xFFFF0000u); }

// ---------------- pass 1: coarse bucket partition (dst>>8), atomic-free ----------------

__launch_bounds__(256)
__global__ void k_p1(const int* __restrict__ ei, int E, int NBK,
                     unsigned* __restrict__ packed, unsigned short* __restrict__ segdesc) {
    __shared__ unsigned sin[EPB];
    __shared__ unsigned sout[EPB];
    __shared__ int hist[257], cur[256], excl[257];
    const int t = threadIdx.x;
    const int e0 = blockIdx.x * EPB;
    const int cnt = min(EPB, E - e0);

    if (t < 256) { hist[t] = 0; cur[t] = 0; }
    if (t == 0) hist[256] = 0;
    __syncthreads();

    for (int i = t; i < cnt; i += 256) {
        int s = ei[e0 + i];
        int d = ei[E + e0 + i];
        sin[i] = ((unsigned)d << 16) | (unsigned)s;   // N < 65536 for both
        atomicAdd(&hist[d >> 8], 1);
    }
    __syncthreads();

    if (t < 64) {  // wave 0: exclusive scan of hist[0..NBK)
        int carry = 0;
        for (int c = 0; c * 64 < NBK; ++c) {
            int idx = c * 64 + t;
            int v = (idx < NBK) ? hist[idx] : 0;
            int x = v;
#pragma unroll
            for (int d = 1; d < 64; d <<= 1) { int y = __shfl_up(x, d, 64); if (t >= d) x += y; }
            if (idx < NBK) excl[idx] = carry + x - v;
            carry += __shfl(x, 63, 64);
        }
        if (t == 0) excl[NBK] = carry;   // == cnt
    }
    __syncthreads();

    for (int i = t; i < cnt; i += 256) {
        unsigned v = sin[i];
        int b = v >> 24;                 // dst >> 8
        int pos = excl[b] + atomicAdd(&cur[b], 1);   // LDS atomic (fast)
        sout[pos] = v;
    }
    __syncthreads();

    for (int i = t; i < cnt; i += 256) packed[(size_t)e0 + i] = sout[i];   // coalesced
    for (int i = t; i <= NBK; i += 256) segdesc[(size_t)blockIdx.x * SDS + i] = (unsigned short)excl[i];
}

// ---------------- pass 2: per-bucket exact CSR (rpB/rpE/dinv/eidx), all in LDS ----------------

__launch_bounds__(256)
__global__ void k_p2(const unsigned* __restrict__ packed, const unsigned short* __restrict__ segdesc,
                     int NB1, unsigned short* __restrict__ eidx,
                     int* __restrict__ rpB, int* __restrict__ rpE,
                     float* __restrict__ dinv, int N) {
    __shared__ unsigned ev[BCAP];
    __shared__ unsigned short se[BCAP];
    __shared__ int lenS[512], offS[513];
    __shared__ int hist[NBINS], cur[NBINS], excl[NBINS + 1];
    const int t = threadIdx.x;
    const int b = blockIdx.x;

    if (t < NBINS) { hist[t] = 0; cur[t] = 0; }
    for (int blk = t; blk < NB1; blk += 256) {
        int s0 = segdesc[(size_t)blk * SDS + b];
        int s1 = segdesc[(size_t)blk * SDS + b + 1];
        lenS[blk] = s1 - s0;
    }
    __syncthreads();

    if (t < 64) {  // wave 0: exclusive scan of lenS[0..NB1)
        int carry = 0;
        for (int c = 0; c * 64 < NB1; ++c) {
            int idx = c * 64 + t;
            int v = (idx < NB1) ? lenS[idx] : 0;
            int x = v;
#pragma unroll
            for (int d = 1; d < 64; d <<= 1) { int y = __shfl_up(x, d, 64); if (t >= d) x += y; }
            if (idx < NB1) offS[idx] = carry + x - v;
            carry += __shfl(x, 63, 64);
        }
        if (t == 0) offS[NB1 < 512 ? NB1 : 512] = carry;
    }
    __syncthreads();
    const int total = min(offS[NB1 < 512 ? NB1 : 512], BCAP);

    for (int blk = t; blk < NB1; blk += 256) {
        int s0 = segdesc[(size_t)blk * SDS + b];
        int l = lenS[blk], o = offS[blk];
        if (o + l > BCAP) l = max(0, BCAP - o);
        const unsigned* sp = packed + (size_t)blk * EPB + s0;
        for (int j = 0; j < l; ++j) ev[o + j] = sp[j];
    }
    __syncthreads();

    for (int i = t; i < total; i += 256) atomicAdd(&hist[(ev[i] >> 16) & 0xFF], 1);
    __syncthreads();

    if (t < 64) {  // wave 0: exclusive scan of hist[0..256)
        int carry = 0;
#pragma unroll
        for (int c = 0; c < 4; ++c) {
            int idx = c * 64 + t;
            int v = hist[idx];
            int x = v;
#pragma unroll
            for (int d = 1; d < 64; d <<= 1) { int y = __shfl_up(x, d, 64); if (t >= d) x += y; }
            excl[idx] = carry + x - v;
            carry += __shfl(x, 63, 64);
        }
        if (t == 0) excl[NBINS] = carry;
    }
    __syncthreads();

    if (t < NBINS) {
        int d = b * NBINS + t;
        if (d < N) {
            int c = hist[t];
            int base = b * BCAP + excl[t];
            rpB[d] = base;
            rpE[d] = base + c;
            dinv[d] = rsqrtf((float)(c + 1));   // +1 self-loop
        }
    }
    for (int i = t; i < total; i += 256) {
        unsigned v = ev[i];
        int l = (v >> 16) & 0xFF;
        int p = excl[l] + atomicAdd(&cur[l], 1);
        se[p] = (unsigned short)(v & 0xFFFF);
    }
    __syncthreads();
    for (int i = t; i < total; i += 256) eidx[(size_t)b * BCAP + i] = se[i];
}

// ---------------- GEMM1 (MFMA): m1p = bf16((x @ W1) * dinv[row]) ----------------
// 64 rows x 64 cols per block, 4 waves = 4 col-strips of 16. K chunked by 128.
// x converted f32->bf16 at stage time; W1 chunk staged transposed [col][k].
// Row stride 136 u16 = 272 B: 16B-aligned b128 reads, banks 4r mod 32 -> 2 lanes/bank (free).
// A/B fragments use the SAME k-index map ((lane>>4)*8+i), so any internal hw
// k-permutation cancels between operands. C/D layout per m89: col=lane&15,
// row=(lane>>4)*4+reg.

__launch_bounds__(256)
__global__ void k_gemm1(const float* __restrict__ x, const float* __restrict__ W1,
                        const float* __restrict__ dinv,
                        unsigned short* __restrict__ m1p, int N) {
    __shared__ __align__(16) unsigned short xb[64][136];
    __shared__ __align__(16) unsigned short wb[64][136];
    const int t    = threadIdx.x;
    const int lane = t & 63;
    const int wv   = t >> 6;        // wave id 0..3 -> col strip
    const int lr   = lane & 15;     // fragment row (A) / col (B)
    const int kg   = lane >> 4;     // k-group 0..3
    const int row0 = blockIdx.x * 64;

    f32x4 acc[4];
#pragma unroll
    for (int rb = 0; rb < 4; rb++) acc[rb] = (f32x4){0.f, 0.f, 0.f, 0.f};

    for (int k0 = 0; k0 < F_IN; k0 += 128) {
        // stage x chunk: 64 rows x 128 k, f32 -> bf16. 1024 groups of 8.
#pragma unroll
        for (int i = 0; i < 4; i++) {
            int g  = t + i * 256;
            int r  = g >> 4;              // row in tile
            int gk = (g & 15) << 3;       // k offset in chunk
            int row = row0 + r;
            short8v p = (short8v){0, 0, 0, 0, 0, 0, 0, 0};
            if (row < N) {
                const float* sp = &x[(size_t)row * F_IN + k0 + gk];
                float4 f0 = *reinterpret_cast<const float4*>(sp);
                float4 f1 = *reinterpret_cast<const float4*>(sp + 4);
                p[0] = (short)f2bf(f0.x); p[1] = (short)f2bf(f0.y);
                p[2] = (short)f2bf(f0.z); p[3] = (short)f2bf(f0.w);
                p[4] = (short)f2bf(f1.x); p[5] = (short)f2bf(f1.y);
                p[6] = (short)f2bf(f1.z); p[7] = (short)f2bf(f1.w);
            }
            *reinterpret_cast<short8v*>(&xb[r][gk]) = p;
        }
        // stage W chunk transposed: wb[col][k], k in [0,128). 1024 groups of 8 cols.
#pragma unroll
        for (int i = 0; i < 4; i++) {
            int g  = t + i * 256;
            int k  = g >> 3;              // k in chunk
            int c0 = (g & 7) << 3;        // col base
            const float* sp = &W1[(size_t)(k0 + k) * 64 + c0];
            float4 f0 = *reinterpret_cast<const float4*>(sp);
            float4 f1 = *reinterpret_cast<const float4*>(sp + 4);
            wb[c0 + 0][k] = f2bf(f0.x); wb[c0 + 1][k] = f2bf(f0.y);
            wb[c0 + 2][k] = f2bf(f0.z); wb[c0 + 3][k] = f2bf(f0.w);
            wb[c0 + 4][k] = f2bf(f1.x); wb[c0 + 5][k] = f2bf(f1.y);
            wb[c0 + 6][k] = f2bf(f1.z); wb[c0 + 7][k] = f2bf(f1.w);
        }
        __syncthreads();

#pragma unroll
        for (int kk = 0; kk < 128; kk += 32) {
            short8v bfrag = *reinterpret_cast<const short8v*>(&wb[(wv << 4) + lr][kk + (kg << 3)]);
#pragma unroll
            for (int rb = 0; rb < 4; rb++) {
                short8v afrag = *reinterpret_cast<const short8v*>(&xb[(rb << 4) + lr][kk + (kg << 3)]);
                acc[rb] = __builtin_amdgcn_mfma_f32_16x16x32_bf16(afrag, bfrag, acc[rb], 0, 0, 0);
            }
        }
        __syncthreads();
    }

    const int col = (wv << 4) + lr;
#pragma unroll
    for (int rb = 0; rb < 4; rb++) {
#pragma unroll
        for (int i = 0; i < 4; i++) {
            int row = row0 + (rb << 4) + (kg << 2) + i;
            if (row < N) m1p[(size_t)row * 64 + col] = f2bf(acc[rb][i] * dinv[row]);
        }
    }
}

// ---------------- CSR gather, 64 bf16 features: half-wave per node, uint loads ----------------

__launch_bounds__(256)
__global__ void k_gather64h(const int* __restrict__ rpB, const int* __restrict__ rpE,
                            const unsigned short* __restrict__ eidx,
                            const unsigned* __restrict__ msg,   // [N][32] packed bf16 pairs
                            float* __restrict__ acc, int N) {
    int w = blockIdx.x * 8 + (threadIdx.x >> 5);
    if (w >= N) return;
    int f = threadIdx.x & 31;
    int i = rpB[w], e = rpE[w];
    unsigned u = msg[(size_t)w * 32 + f];           // self-loop
    float l0 = bflo(u), h0 = bfhi(u);
    float l1 = 0.f, h1 = 0.f, l2 = 0.f, h2 = 0.f, l3 = 0.f, h3 = 0.f;
    for (; i + 4 <= e; i += 4) {
        unsigned u0 = msg[(size_t)eidx[i]     * 32 + f];
        unsigned u1 = msg[(size_t)eidx[i + 1] * 32 + f];
        unsigned u2 = msg[(size_t)eidx[i + 2] * 32 + f];
        unsigned u3 = msg[(size_t)eidx[i + 3] * 32 + f];
        l0 += bflo(u0); h0 += bfhi(u0);
        l1 += bflo(u1); h1 += bfhi(u1);
        l2 += bflo(u2); h2 += bfhi(u2);
        l3 += bflo(u3); h3 += bfhi(u3);
    }
    for (; i < e; i++) {
        unsigned u0 = msg[(size_t)eidx[i] * 32 + f];
        l0 += bflo(u0); h0 += bfhi(u0);
    }
    *reinterpret_cast<float2*>(&acc[(size_t)w * 64 + (f << 1)]) =
        make_float2((l0 + l1) + (l2 + l3), (h0 + h1) + (h2 + h3));
}

// ---------------- CSR gather, 32 bf16 features: 16 lanes per node, uint loads ----------------

__launch_bounds__(256)
__global__ void k_gather32h(const int* __restrict__ rpB, const int* __restrict__ rpE,
                            const unsigned short* __restrict__ eidx,
                            const unsigned* __restrict__ msg,   // [N][16] packed bf16 pairs
                            void* __restrict__ outp, int N,
                            const float* __restrict__ bias, const float* __restrict__ dinv) {
    int w = blockIdx.x * 16 + (threadIdx.x >> 4);
    if (w >= N) return;
    int f = threadIdx.x & 15;
    int i = rpB[w], e = rpE[w];
    unsigned u = msg[(size_t)w * 16 + f];           // self-loop
    float l0 = bflo(u), h0 = bfhi(u);
    float l1 = 0.f, h1 = 0.f, l2 = 0.f, h2 = 0.f, l3 = 0.f, h3 = 0.f;
    for (; i + 4 <= e; i += 4) {
        unsigned u0 = msg[(size_t)eidx[i]     * 16 + f];
        unsigned u1 = msg[(size_t)eidx[i + 1] * 16 + f];
        unsigned u2 = msg[(size_t)eidx[i + 2] * 16 + f];
        unsigned u3 = msg[(size_t)eidx[i + 3] * 16 + f];
        l0 += bflo(u0); h0 += bfhi(u0);
        l1 += bflo(u1); h1 += bfhi(u1);
        l2 += bflo(u2); h2 += bfhi(u2);
        l3 += bflo(u3); h3 += bfhi(u3);
    }
    for (; i < e; i++) {
        unsigned u0 = msg[(size_t)eidx[i] * 16 + f];
        l0 += bflo(u0); h0 += bfhi(u0);
    }
    float rl = (l0 + l1) + (l2 + l3);
    float rh = (h0 + h1) + (h2 + h3);
    if (bias) {
        float s = dinv[w];
        rl = fmaxf(rl * s + bias[(f << 1)], 0.f) * s;
        rh = fmaxf(rh * s + bias[(f << 1) + 1], 0.f) * s;
        ((unsigned*)outp)[(size_t)w * 16 + f] = (unsigned)f2bf(rl) | ((unsigned)f2bf(rh) << 16);
    } else {
        ((float2*)outp)[(size_t)w * 16 + f] = make_float2(rl, rh);
    }
}

// ---------------- layer2: h1 = relu(s*acc1 + b1); m2p = bf16((h1@W2)*s) ----------------

__launch_bounds__(256)
__global__ void k_layer2(const float* __restrict__ acc1, const float* __restrict__ W2,
                         const float* __restrict__ b1, const float* __restrict__ dinv,
                         unsigned short* __restrict__ m2p, int N) {
    __shared__ float h1t[64][64];
    __shared__ float w2t[64][32];
    const int t = threadIdx.x;
    const int row0 = blockIdx.x * 64;
#pragma unroll
    for (int i = 0; i < 16; i++) {
        int lin = i * 256 + t;
        int r = lin >> 6, c = lin & 63;
        int row = row0 + r;
        float v = 0.f;
        if (row < N) v = fmaxf(acc1[(size_t)row * 64 + c] * dinv[row] + b1[c], 0.f);
        h1t[r][c] = v;
    }
#pragma unroll
    for (int i = 0; i < 8; i++) {
        int lin = i * 256 + t;
        w2t[lin >> 5][lin & 31] = W2[lin];
    }
    __syncthreads();
    const int tx = t & 31, ty = t >> 5;
#pragma unroll
    for (int rr = 0; rr < 8; rr++) {
        int r = rr * 8 + ty;
        float a = 0.f;
#pragma unroll
        for (int k = 0; k < 64; k++) a += h1t[r][k] * w2t[k][tx];
        int row = row0 + r;
        if (row < N) m2p[(size_t)row * 32 + tx] = f2bf(a * dinv[row]);
    }
}

// ---------------- out: wave-per-8-rows GEMV, W3 in LDS, coalesced row stores ----------------

__launch_bounds__(512, 5)
__global__ void k_out(const float* __restrict__ acc3, const float* __restrict__ W3,
                      const float* __restrict__ b3, const float* __restrict__ dinv,
                      float* __restrict__ out, int N, int total_waves) {
    __shared__ float w3t[32 * 385];
    const int t = threadIdx.x;
    for (int i = t; i < 32 * 385; i += 512) w3t[i] = W3[i];
    __syncthreads();

    const int lane = t & 63;
    const int wv = blockIdx.x * 8 + (t >> 6);
    const int half = lane >> 5;        // 0 or 1
    const int feat = lane & 31;

    float bias[6];
#pragma unroll
    for (int c = 0; c < 6; c++) bias[c] = b3[lane + 64 * c];
    const float bias384 = b3[384];

    for (int r0 = wv * 8; r0 < N; r0 += total_waves * 8) {
        float gv[4];
#pragma unroll
        for (int j = 0; j < 4; j++) {
            int r = r0 + 2 * j + half;
            gv[j] = (r < N) ? acc3[(size_t)r * 32 + feat] * dinv[r] : 0.f;
        }

        float a[8][6], ax[8];
#pragma unroll
        for (int r = 0; r < 8; r++) {
#pragma unroll
            for (int c = 0; c < 6; c++) a[r][c] = bias[c];
            ax[r] = bias384;
        }

#pragma unroll 2
        for (int k = 0; k < 32; k++) {
            float g[8];
#pragma unroll
            for (int j = 0; j < 4; j++) {
                g[2 * j]     = __shfl(gv[j], k, 64);
                g[2 * j + 1] = __shfl(gv[j], 32 + k, 64);
            }
            const float* wrow = &w3t[k * 385];
            float w[6];
#pragma unroll
            for (int c = 0; c < 6; c++) w[c] = wrow[lane + 64 * c];
            float wx = wrow[384];   // uniform -> LDS broadcast
#pragma unroll
            for (int r = 0; r < 8; r++) {
#pragma unroll
                for (int c = 0; c < 6; c++) a[r][c] += g[r] * w[c];
                ax[r] += g[r] * wx;
            }
        }

#pragma unroll
        for (int r = 0; r < 8; r++) {
            int row = r0 + r;
            if (row < N) {
                size_t ob = (size_t)row * 385;
                float v0 = a[r][0];
                if (lane == 0) v0 = 1.0f / (1.0f + expf(-v0));
                out[ob + lane] = v0;
#pragma unroll
                for (int c = 1; c < 6; c++) out[ob + lane + 64 * c] = a[r][c];
                if (lane == 0) out[ob + 384] = ax[r];
            }
        }
    }
}

extern "C" void kernel_launch(void* const* d_in, const int* in_sizes, int n_in,
                              void* d_out, int out_size, void* d_ws, size_t ws_size,
                              hipStream_t stream) {
    const float* x  = (const float*)d_in[0];
    const int*   ei = (const int*)d_in[1];
    const float* W1 = (const float*)d_in[2];
    const float* b1 = (const float*)d_in[3];
    const float* W2 = (const float*)d_in[4];
    const float* b2 = (const float*)d_in[5];
    const float* W3 = (const float*)d_in[6];
    const float* b3 = (const float*)d_in[7];
    float* out = (float*)d_out;

    const int N = in_sizes[0] / F_IN;   // 50000
    const int E = in_sizes[1] / 2;      // 1600000
    const int NB1 = (E + EPB - 1) / EPB;       // 391 pass-1 blocks
    const int NBK = (N + NBINS - 1) / NBINS;   // 196 coarse buckets

    float* ws   = (float*)d_ws;
    float* dinv = ws;
    float* bufA = ws + N;
    float* bufB = bufA + (size_t)64 * N;
    int*   rpB  = (int*)(bufB + (size_t)64 * N);
    int*   rpE  = rpB + N;
    unsigned short* eidx    = (unsigned short*)(rpE + N);
    unsigned short* segdesc = eidx + (size_t)NBK * BCAP;

    unsigned* packed = (unsigned*)bufA;              // E u32; dead after k_p2
    unsigned short* m1p = (unsigned short*)bufA;     // [N,64] bf16 (6.4 MB)
    float* acc1 = bufB;                              // [N,64] f32
    unsigned short* m2p = (unsigned short*)bufA;     // [N,32] bf16
    unsigned short* h2p = (unsigned short*)bufB;     // [N,32] bf16 (acc1 dead)
    float* acc3 = bufA + (size_t)32 * N;             // [N,32] f32 (distinct from m2p region)

    k_p1<<<NB1, 256, 0, stream>>>(ei, E, NBK, packed, segdesc);
    k_p2<<<NBK, 256, 0, stream>>>(packed, segdesc, NB1, eidx, rpB, rpE, dinv, N);

    k_gemm1    <<<(N + 63) / 64, 256, 0, stream>>>(x, W1, dinv, m1p, N);
    k_gather64h<<<(N + 7) / 8, 256, 0, stream>>>(rpB, rpE, eidx, (const unsigned*)m1p, acc1, N);

    k_layer2   <<<(N + 63) / 64, 256, 0, stream>>>(acc1, W2, b1, dinv, m2p, N);
    k_gather32h<<<(N + 15) / 16, 256, 0, stream>>>(rpB, rpE, eidx, (const unsigned*)m2p,
                                                   (void*)h2p, N, b2, dinv);   // fused mid3, bf16 out

    k_gather32h<<<(N + 15) / 16, 256, 0, stream>>>(rpB, rpE, eidx, (const unsigned*)h2p,
                                                   (void*)acc3, N, nullptr, dinv);

    const int OUT_BLOCKS = 512;
    k_out<<<OUT_BLOCKS, 512, 0, stream>>>(acc3, W3, b3, dinv, out, N, OUT_BLOCKS * 8);
}

// Round 9
// 189.762 us; speedup vs baseline: 1.8896x; 1.0366x over previous
//
#include <hip/hip_runtime.h>

#define F_IN  384
#define EPB   4096   // edges per block, pass 1
#define NBINS 256    // dsts per coarse bucket
#define BCAP  12288  // eidx region stride per bucket (avg 8163, huge safety margin)
#define SDS   208    // segdesc row stride (u16 entries), >= NBK+1

typedef __attribute__((ext_vector_type(8))) short short8v;   // bf16x8 MFMA fragment
typedef __attribute__((ext_vector_type(4))) float f32x4;     // MFMA accumulator

// bf16 helpers (RNE), no header-type dependence
__device__ __forceinline__ unsigned short f2bf(float f) {
    unsigned u = __float_as_uint(f);
    return (unsigned short)((u + 0x7FFFu + ((u >> 16) & 1u)) >> 16);
}
__device__ __forceinline__ float bflo(unsigned u) { return __uint_as_float(u << 16); }
__device__ __forceinline__ float bfhi(unsigned u) { return __uint_as_float(u & 0xFFFF0000u); }

// ---------------- pass 1: coarse bucket partition (dst>>8), atomic-free ----------------

__launch_bounds__(256)
__global__ void k_p1(const int* __restrict__ ei, int E, int NBK,
                     unsigned* __restrict__ packed, unsigned short* __restrict__ segdesc) {
    __shared__ unsigned sin[EPB];
    __shared__ unsigned sout[EPB];
    __shared__ int hist[257], cur[256], excl[257];
    const int t = threadIdx.x;
    const int e0 = blockIdx.x * EPB;
    const int cnt = min(EPB, E - e0);

    if (t < 256) { hist[t] = 0; cur[t] = 0; }
    if (t == 0) hist[256] = 0;
    __syncthreads();

    for (int i = t; i < cnt; i += 256) {
        int s = ei[e0 + i];
        int d = ei[E + e0 + i];
        sin[i] = ((unsigned)d << 16) | (unsigned)s;   // N < 65536 for both
        atomicAdd(&hist[d >> 8], 1);
    }
    __syncthreads();

    if (t < 64) {  // wave 0: exclusive scan of hist[0..NBK)
        int carry = 0;
        for (int c = 0; c * 64 < NBK; ++c) {
            int idx = c * 64 + t;
            int v = (idx < NBK) ? hist[idx] : 0;
            int x = v;
#pragma unroll
            for (int d = 1; d < 64; d <<= 1) { int y = __shfl_up(x, d, 64); if (t >= d) x += y; }
            if (idx < NBK) excl[idx] = carry + x - v;
            carry += __shfl(x, 63, 64);
        }
        if (t == 0) excl[NBK] = carry;   // == cnt
    }
    __syncthreads();

    for (int i = t; i < cnt; i += 256) {
        unsigned v = sin[i];
        int b = v >> 24;                 // dst >> 8
        int pos = excl[b] + atomicAdd(&cur[b], 1);   // LDS atomic (fast)
        sout[pos] = v;
    }
    __syncthreads();

    for (int i = t; i < cnt; i += 256) packed[(size_t)e0 + i] = sout[i];   // coalesced
    for (int i = t; i <= NBK; i += 256) segdesc[(size_t)blockIdx.x * SDS + i] = (unsigned short)excl[i];
}

// ---------------- pass 2: per-bucket exact CSR (rpB/rpE/dinv/eidx), all in LDS ----------------

__launch_bounds__(256)
__global__ void k_p2(const unsigned* __restrict__ packed, const unsigned short* __restrict__ segdesc,
                     int NB1, unsigned short* __restrict__ eidx,
                     int* __restrict__ rpB, int* __restrict__ rpE,
                     float* __restrict__ dinv, int N) {
    __shared__ unsigned ev[BCAP];
    __shared__ unsigned short se[BCAP];
    __shared__ int lenS[512], offS[513];
    __shared__ int hist[NBINS], cur[NBINS], excl[NBINS + 1];
    const int t = threadIdx.x;
    const int b = blockIdx.x;

    if (t < NBINS) { hist[t] = 0; cur[t] = 0; }
    for (int blk = t; blk < NB1; blk += 256) {
        int s0 = segdesc[(size_t)blk * SDS + b];
        int s1 = segdesc[(size_t)blk * SDS + b + 1];
        lenS[blk] = s1 - s0;
    }
    __syncthreads();

    if (t < 64) {  // wave 0: exclusive scan of lenS[0..NB1)
        int carry = 0;
        for (int c = 0; c * 64 < NB1; ++c) {
            int idx = c * 64 + t;
            int v = (idx < NB1) ? lenS[idx] : 0;
            int x = v;
#pragma unroll
            for (int d = 1; d < 64; d <<= 1) { int y = __shfl_up(x, d, 64); if (t >= d) x += y; }
            if (idx < NB1) offS[idx] = carry + x - v;
            carry += __shfl(x, 63, 64);
        }
        if (t == 0) offS[NB1 < 512 ? NB1 : 512] = carry;
    }
    __syncthreads();
    const int total = min(offS[NB1 < 512 ? NB1 : 512], BCAP);

    for (int blk = t; blk < NB1; blk += 256) {
        int s0 = segdesc[(size_t)blk * SDS + b];
        int l = lenS[blk], o = offS[blk];
        if (o + l > BCAP) l = max(0, BCAP - o);
        const unsigned* sp = packed + (size_t)blk * EPB + s0;
        for (int j = 0; j < l; ++j) ev[o + j] = sp[j];
    }
    __syncthreads();

    for (int i = t; i < total; i += 256) atomicAdd(&hist[(ev[i] >> 16) & 0xFF], 1);
    __syncthreads();

    if (t < 64) {  // wave 0: exclusive scan of hist[0..256)
        int carry = 0;
#pragma unroll
        for (int c = 0; c < 4; ++c) {
            int idx = c * 64 + t;
            int v = hist[idx];
            int x = v;
#pragma unroll
            for (int d = 1; d < 64; d <<= 1) { int y = __shfl_up(x, d, 64); if (t >= d) x += y; }
            excl[idx] = carry + x - v;
            carry += __shfl(x, 63, 64);
        }
        if (t == 0) excl[NBINS] = carry;
    }
    __syncthreads();

    if (t < NBINS) {
        int d = b * NBINS + t;
        if (d < N) {
            int c = hist[t];
            int base = b * BCAP + excl[t];
            rpB[d] = base;
            rpE[d] = base + c;
            dinv[d] = rsqrtf((float)(c + 1));   // +1 self-loop
        }
    }
    for (int i = t; i < total; i += 256) {
        unsigned v = ev[i];
        int l = (v >> 16) & 0xFF;
        int p = excl[l] + atomicAdd(&cur[l], 1);
        se[p] = (unsigned short)(v & 0xFFFF);
    }
    __syncthreads();
    for (int i = t; i < total; i += 256) eidx[(size_t)b * BCAP + i] = se[i];
}

// ---------------- GEMM1 (MFMA): m1p = bf16((x @ W1) * dinv[row]) ----------------

__launch_bounds__(256)
__global__ void k_gemm1(const float* __restrict__ x, const float* __restrict__ W1,
                        const float* __restrict__ dinv,
                        unsigned short* __restrict__ m1p, int N) {
    __shared__ __align__(16) unsigned short xb[64][136];
    __shared__ __align__(16) unsigned short wb[64][136];
    const int t    = threadIdx.x;
    const int lane = t & 63;
    const int wv   = t >> 6;        // wave id 0..3 -> col strip
    const int lr   = lane & 15;     // fragment row (A) / col (B)
    const int kg   = lane >> 4;     // k-group 0..3
    const int row0 = blockIdx.x * 64;

    f32x4 acc[4];
#pragma unroll
    for (int rb = 0; rb < 4; rb++) acc[rb] = (f32x4){0.f, 0.f, 0.f, 0.f};

    for (int k0 = 0; k0 < F_IN; k0 += 128) {
        // stage x chunk: 64 rows x 128 k, f32 -> bf16. 1024 groups of 8.
#pragma unroll
        for (int i = 0; i < 4; i++) {
            int g  = t + i * 256;
            int r  = g >> 4;              // row in tile
            int gk = (g & 15) << 3;       // k offset in chunk
            int row = row0 + r;
            short8v p = (short8v){0, 0, 0, 0, 0, 0, 0, 0};
            if (row < N) {
                const float* sp = &x[(size_t)row * F_IN + k0 + gk];
                float4 f0 = *reinterpret_cast<const float4*>(sp);
                float4 f1 = *reinterpret_cast<const float4*>(sp + 4);
                p[0] = (short)f2bf(f0.x); p[1] = (short)f2bf(f0.y);
                p[2] = (short)f2bf(f0.z); p[3] = (short)f2bf(f0.w);
                p[4] = (short)f2bf(f1.x); p[5] = (short)f2bf(f1.y);
                p[6] = (short)f2bf(f1.z); p[7] = (short)f2bf(f1.w);
            }
            *reinterpret_cast<short8v*>(&xb[r][gk]) = p;
        }
        // stage W chunk transposed: wb[col][k], k in [0,128). 1024 groups of 8 cols.
#pragma unroll
        for (int i = 0; i < 4; i++) {
            int g  = t + i * 256;
            int k  = g >> 3;              // k in chunk
            int c0 = (g & 7) << 3;        // col base
            const float* sp = &W1[(size_t)(k0 + k) * 64 + c0];
            float4 f0 = *reinterpret_cast<const float4*>(sp);
            float4 f1 = *reinterpret_cast<const float4*>(sp + 4);
            wb[c0 + 0][k] = f2bf(f0.x); wb[c0 + 1][k] = f2bf(f0.y);
            wb[c0 + 2][k] = f2bf(f0.z); wb[c0 + 3][k] = f2bf(f0.w);
            wb[c0 + 4][k] = f2bf(f1.x); wb[c0 + 5][k] = f2bf(f1.y);
            wb[c0 + 6][k] = f2bf(f1.z); wb[c0 + 7][k] = f2bf(f1.w);
        }
        __syncthreads();

#pragma unroll
        for (int kk = 0; kk < 128; kk += 32) {
            short8v bfrag = *reinterpret_cast<const short8v*>(&wb[(wv << 4) + lr][kk + (kg << 3)]);
#pragma unroll
            for (int rb = 0; rb < 4; rb++) {
                short8v afrag = *reinterpret_cast<const short8v*>(&xb[(rb << 4) + lr][kk + (kg << 3)]);
                acc[rb] = __builtin_amdgcn_mfma_f32_16x16x32_bf16(afrag, bfrag, acc[rb], 0, 0, 0);
            }
        }
        __syncthreads();
    }

    const int col = (wv << 4) + lr;
#pragma unroll
    for (int rb = 0; rb < 4; rb++) {
#pragma unroll
        for (int i = 0; i < 4; i++) {
            int row = row0 + (rb << 4) + (kg << 2) + i;
            if (row < N) m1p[(size_t)row * 64 + col] = f2bf(acc[rb][i] * dinv[row]);
        }
    }
}

// ---------------- CSR gather, 64 bf16 features: half-wave per node, uint loads ----------------

__launch_bounds__(256)
__global__ void k_gather64h(const int* __restrict__ rpB, const int* __restrict__ rpE,
                            const unsigned short* __restrict__ eidx,
                            const unsigned* __restrict__ msg,   // [N][32] packed bf16 pairs
                            float* __restrict__ acc, int N) {
    int w = blockIdx.x * 8 + (threadIdx.x >> 5);
    if (w >= N) return;
    int f = threadIdx.x & 31;
    int i = rpB[w], e = rpE[w];
    unsigned u = msg[(size_t)w * 32 + f];           // self-loop
    float l0 = bflo(u), h0 = bfhi(u);
    float l1 = 0.f, h1 = 0.f, l2 = 0.f, h2 = 0.f, l3 = 0.f, h3 = 0.f;
    for (; i + 4 <= e; i += 4) {
        unsigned u0 = msg[(size_t)eidx[i]     * 32 + f];
        unsigned u1 = msg[(size_t)eidx[i + 1] * 32 + f];
        unsigned u2 = msg[(size_t)eidx[i + 2] * 32 + f];
        unsigned u3 = msg[(size_t)eidx[i + 3] * 32 + f];
        l0 += bflo(u0); h0 += bfhi(u0);
        l1 += bflo(u1); h1 += bfhi(u1);
        l2 += bflo(u2); h2 += bfhi(u2);
        l3 += bflo(u3); h3 += bfhi(u3);
    }
    for (; i < e; i++) {
        unsigned u0 = msg[(size_t)eidx[i] * 32 + f];
        l0 += bflo(u0); h0 += bfhi(u0);
    }
    *reinterpret_cast<float2*>(&acc[(size_t)w * 64 + (f << 1)]) =
        make_float2((l0 + l1) + (l2 + l3), (h0 + h1) + (h2 + h3));
}

// ---------------- CSR gather, 32 bf16 features: 16 lanes per node, uint loads ----------------

__launch_bounds__(256)
__global__ void k_gather32h(const int* __restrict__ rpB, const int* __restrict__ rpE,
                            const unsigned short* __restrict__ eidx,
                            const unsigned* __restrict__ msg,   // [N][16] packed bf16 pairs
                            void* __restrict__ outp, int N,
                            const float* __restrict__ bias, const float* __restrict__ dinv) {
    int w = blockIdx.x * 16 + (threadIdx.x >> 4);
    if (w >= N) return;
    int f = threadIdx.x & 15;
    int i = rpB[w], e = rpE[w];
    unsigned u = msg[(size_t)w * 16 + f];           // self-loop
    float l0 = bflo(u), h0 = bfhi(u);
    float l1 = 0.f, h1 = 0.f, l2 = 0.f, h2 = 0.f, l3 = 0.f, h3 = 0.f;
    for (; i + 4 <= e; i += 4) {
        unsigned u0 = msg[(size_t)eidx[i]     * 16 + f];
        unsigned u1 = msg[(size_t)eidx[i + 1] * 16 + f];
        unsigned u2 = msg[(size_t)eidx[i + 2] * 16 + f];
        unsigned u3 = msg[(size_t)eidx[i + 3] * 16 + f];
        l0 += bflo(u0); h0 += bfhi(u0);
        l1 += bflo(u1); h1 += bfhi(u1);
        l2 += bflo(u2); h2 += bfhi(u2);
        l3 += bflo(u3); h3 += bfhi(u3);
    }
    for (; i < e; i++) {
        unsigned u0 = msg[(size_t)eidx[i] * 16 + f];
        l0 += bflo(u0); h0 += bfhi(u0);
    }
    float rl = (l0 + l1) + (l2 + l3);
    float rh = (h0 + h1) + (h2 + h3);
    if (bias) {
        float s = dinv[w];
        rl = fmaxf(rl * s + bias[(f << 1)], 0.f) * s;
        rh = fmaxf(rh * s + bias[(f << 1) + 1], 0.f) * s;
        ((unsigned*)outp)[(size_t)w * 16 + f] = (unsigned)f2bf(rl) | ((unsigned)f2bf(rh) << 16);
    } else {
        ((float2*)outp)[(size_t)w * 16 + f] = make_float2(rl, rh);
    }
}

// ---------------- layer2: h1 = relu(s*acc1 + b1); m2p = bf16((h1@W2)*s) ----------------

__launch_bounds__(256)
__global__ void k_layer2(const float* __restrict__ acc1, const float* __restrict__ W2,
                         const float* __restrict__ b1, const float* __restrict__ dinv,
                         unsigned short* __restrict__ m2p, int N) {
    __shared__ float h1t[64][64];
    __shared__ float w2t[64][32];
    const int t = threadIdx.x;
    const int row0 = blockIdx.x * 64;
#pragma unroll
    for (int i = 0; i < 16; i++) {
        int lin = i * 256 + t;
        int r = lin >> 6, c = lin & 63;
        int row = row0 + r;
        float v = 0.f;
        if (row < N) v = fmaxf(acc1[(size_t)row * 64 + c] * dinv[row] + b1[c], 0.f);
        h1t[r][c] = v;
    }
#pragma unroll
    for (int i = 0; i < 8; i++) {
        int lin = i * 256 + t;
        w2t[lin >> 5][lin & 31] = W2[lin];
    }
    __syncthreads();
    const int tx = t & 31, ty = t >> 5;
#pragma unroll
    for (int rr = 0; rr < 8; rr++) {
        int r = rr * 8 + ty;
        float a = 0.f;
#pragma unroll
        for (int k = 0; k < 64; k++) a += h1t[r][k] * w2t[k][tx];
        int row = row0 + r;
        if (row < N) m2p[(size_t)row * 32 + tx] = f2bf(a * dinv[row]);
    }
}

// ---------------- out: wave-per-8-rows GEMV, W3 read from L2 (no LDS), nt stores ----------------
// out[row] = (dinv[row]*acc3[row]) @ W3 + b3; sigmoid on col 0.
// W3 (49 KB) is L2-resident; reading it directly removes the LDS stage that was
// capping occupancy at ~1 block/CU. 256-thread blocks, zero LDS, VGPR-capped only.

__launch_bounds__(256, 4)
__global__ void k_out(const float* __restrict__ acc3, const float* __restrict__ W3,
                      const float* __restrict__ b3, const float* __restrict__ dinv,
                      float* __restrict__ out, int N, int total_waves) {
    const int t = threadIdx.x;
    const int lane = t & 63;
    const int wv = blockIdx.x * 4 + (t >> 6);
    const int half = lane >> 5;        // 0 or 1
    const int feat = lane & 31;

    float bias[6];
#pragma unroll
    for (int c = 0; c < 6; c++) bias[c] = b3[lane + 64 * c];
    const float bias384 = b3[384];

    for (int r0 = wv * 8; r0 < N; r0 += total_waves * 8) {
        // gv[j]: lane holds g[row r0+2j+half][feat]
        float gv[4];
#pragma unroll
        for (int j = 0; j < 4; j++) {
            int r = r0 + 2 * j + half;
            gv[j] = (r < N) ? acc3[(size_t)r * 32 + feat] * dinv[r] : 0.f;
        }

        float a[8][6], ax[8];
#pragma unroll
        for (int r = 0; r < 8; r++) {
#pragma unroll
            for (int c = 0; c < 6; c++) a[r][c] = bias[c];
            ax[r] = bias384;
        }

#pragma unroll 4
        for (int k = 0; k < 32; k++) {
            float g[8];
#pragma unroll
            for (int j = 0; j < 4; j++) {
                g[2 * j]     = __shfl(gv[j], k, 64);
                g[2 * j + 1] = __shfl(gv[j], 32 + k, 64);
            }
            const float* wrow = &W3[k * 385];
            float w[6];
#pragma unroll
            for (int c = 0; c < 6; c++) w[c] = wrow[lane + 64 * c];   // L2-hit, coalesced 256B
            float wx = wrow[384];   // uniform -> scalar load
#pragma unroll
            for (int r = 0; r < 8; r++) {
#pragma unroll
                for (int c = 0; c < 6; c++) a[r][c] += g[r] * w[c];
                ax[r] += g[r] * wx;
            }
        }

#pragma unroll
        for (int r = 0; r < 8; r++) {
            int row = r0 + r;
            if (row < N) {
                size_t ob = (size_t)row * 385;
                float v0 = a[r][0];
                if (lane == 0) v0 = 1.0f / (1.0f + expf(-v0));
                __builtin_nontemporal_store(v0, &out[ob + lane]);
#pragma unroll
                for (int c = 1; c < 6; c++)
                    __builtin_nontemporal_store(a[r][c], &out[ob + lane + 64 * c]);
                if (lane == 0) __builtin_nontemporal_store(ax[r], &out[ob + 384]);
            }
        }
    }
}

extern "C" void kernel_launch(void* const* d_in, const int* in_sizes, int n_in,
                              void* d_out, int out_size, void* d_ws, size_t ws_size,
                              hipStream_t stream) {
    const float* x  = (const float*)d_in[0];
    const int*   ei = (const int*)d_in[1];
    const float* W1 = (const float*)d_in[2];
    const float* b1 = (const float*)d_in[3];
    const float* W2 = (const float*)d_in[4];
    const float* b2 = (const float*)d_in[5];
    const float* W3 = (const float*)d_in[6];
    const float* b3 = (const float*)d_in[7];
    float* out = (float*)d_out;

    const int N = in_sizes[0] / F_IN;   // 50000
    const int E = in_sizes[1] / 2;      // 1600000
    const int NB1 = (E + EPB - 1) / EPB;       // 391 pass-1 blocks
    const int NBK = (N + NBINS - 1) / NBINS;   // 196 coarse buckets

    float* ws   = (float*)d_ws;
    float* dinv = ws;
    float* bufA = ws + N;
    float* bufB = bufA + (size_t)64 * N;
    int*   rpB  = (int*)(bufB + (size_t)64 * N);
    int*   rpE  = rpB + N;
    unsigned short* eidx    = (unsigned short*)(rpE + N);
    unsigned short* segdesc = eidx + (size_t)NBK * BCAP;

    unsigned* packed = (unsigned*)bufA;              // E u32; dead after k_p2
    unsigned short* m1p = (unsigned short*)bufA;     // [N,64] bf16 (6.4 MB)
    float* acc1 = bufB;                              // [N,64] f32
    unsigned short* m2p = (unsigned short*)bufA;     // [N,32] bf16
    unsigned short* h2p = (unsigned short*)bufB;     // [N,32] bf16 (acc1 dead)
    float* acc3 = bufA + (size_t)32 * N;             // [N,32] f32 (distinct from m2p region)

    k_p1<<<NB1, 256, 0, stream>>>(ei, E, NBK, packed, segdesc);
    k_p2<<<NBK, 256, 0, stream>>>(packed, segdesc, NB1, eidx, rpB, rpE, dinv, N);

    k_gemm1    <<<(N + 63) / 64, 256, 0, stream>>>(x, W1, dinv, m1p, N);
    k_gather64h<<<(N + 7) / 8, 256, 0, stream>>>(rpB, rpE, eidx, (const unsigned*)m1p, acc1, N);

    k_layer2   <<<(N + 63) / 64, 256, 0, stream>>>(acc1, W2, b1, dinv, m2p, N);
    k_gather32h<<<(N + 15) / 16, 256, 0, stream>>>(rpB, rpE, eidx, (const unsigned*)m2p,
                                                   (void*)h2p, N, b2, dinv);   // fused mid3, bf16 out

    k_gather32h<<<(N + 15) / 16, 256, 0, stream>>>(rpB, rpE, eidx, (const unsigned*)h2p,
                                                   (void*)acc3, N, nullptr, dinv);

    const int OUT_BLOCKS = 1024;
    k_out<<<OUT_BLOCKS, 256, 0, stream>>>(acc3, W3, b3, dinv, out, N, OUT_BLOCKS * 4);
}

// Round 10
// 176.233 us; speedup vs baseline: 2.0346x; 1.0768x over previous
//
#include <hip/hip_runtime.h>

#define F_IN  384
#define EPB   4096   // edges per block, pass 1
#define NBINS 256    // dsts per coarse bucket
#define BCAP  12288  // eidx region stride per bucket (avg 8163, huge safety margin)
#define SDS   208    // segdesc row stride (u16 entries), >= NBK+1

typedef __attribute__((ext_vector_type(8))) short short8v;   // bf16x8 MFMA fragment
typedef __attribute__((ext_vector_type(4))) float f32x4;     // MFMA accumulator

// bf16 helpers (RNE), no header-type dependence
__device__ __forceinline__ unsigned short f2bf(float f) {
    unsigned u = __float_as_uint(f);
    return (unsigned short)((u + 0x7FFFu + ((u >> 16) & 1u)) >> 16);
}
__device__ __forceinline__ float bflo(unsigned u) { return __uint_as_float(u << 16); }
__device__ __forceinline__ float bfhi(unsigned u) { return __uint_as_float(u & 0xFFFF0000u); }

// ---------------- pass 1: coarse bucket partition (dst>>8), atomic-free ----------------

__launch_bounds__(256)
__global__ void k_p1(const int* __restrict__ ei, int E, int NBK,
                     unsigned* __restrict__ packed, unsigned short* __restrict__ segdesc) {
    __shared__ unsigned sin[EPB];
    __shared__ unsigned sout[EPB];
    __shared__ int hist[257], cur[256], excl[257];
    const int t = threadIdx.x;
    const int e0 = blockIdx.x * EPB;
    const int cnt = min(EPB, E - e0);

    if (t < 256) { hist[t] = 0; cur[t] = 0; }
    if (t == 0) hist[256] = 0;
    __syncthreads();

    for (int i = t; i < cnt; i += 256) {
        int s = ei[e0 + i];
        int d = ei[E + e0 + i];
        sin[i] = ((unsigned)d << 16) | (unsigned)s;   // N < 65536 for both
        atomicAdd(&hist[d >> 8], 1);
    }
    __syncthreads();

    if (t < 64) {  // wave 0: exclusive scan of hist[0..NBK)
        int carry = 0;
        for (int c = 0; c * 64 < NBK; ++c) {
            int idx = c * 64 + t;
            int v = (idx < NBK) ? hist[idx] : 0;
            int x = v;
#pragma unroll
            for (int d = 1; d < 64; d <<= 1) { int y = __shfl_up(x, d, 64); if (t >= d) x += y; }
            if (idx < NBK) excl[idx] = carry + x - v;
            carry += __shfl(x, 63, 64);
        }
        if (t == 0) excl[NBK] = carry;   // == cnt
    }
    __syncthreads();

    for (int i = t; i < cnt; i += 256) {
        unsigned v = sin[i];
        int b = v >> 24;                 // dst >> 8
        int pos = excl[b] + atomicAdd(&cur[b], 1);   // LDS atomic (fast)
        sout[pos] = v;
    }
    __syncthreads();

    for (int i = t; i < cnt; i += 256) packed[(size_t)e0 + i] = sout[i];   // coalesced
    for (int i = t; i <= NBK; i += 256) segdesc[(size_t)blockIdx.x * SDS + i] = (unsigned short)excl[i];
}

// ---------------- pass 2: per-bucket exact CSR (rpB/rpE/dinv/eidx), all in LDS ----------------

__launch_bounds__(256)
__global__ void k_p2(const unsigned* __restrict__ packed, const unsigned short* __restrict__ segdesc,
                     int NB1, unsigned short* __restrict__ eidx,
                     int* __restrict__ rpB, int* __restrict__ rpE,
                     float* __restrict__ dinv, int N) {
    __shared__ unsigned ev[BCAP];
    __shared__ unsigned short se[BCAP];
    __shared__ int lenS[512], offS[513];
    __shared__ int hist[NBINS], cur[NBINS], excl[NBINS + 1];
    const int t = threadIdx.x;
    const int b = blockIdx.x;

    if (t < NBINS) { hist[t] = 0; cur[t] = 0; }
    for (int blk = t; blk < NB1; blk += 256) {
        int s0 = segdesc[(size_t)blk * SDS + b];
        int s1 = segdesc[(size_t)blk * SDS + b + 1];
        lenS[blk] = s1 - s0;
    }
    __syncthreads();

    if (t < 64) {  // wave 0: exclusive scan of lenS[0..NB1)
        int carry = 0;
        for (int c = 0; c * 64 < NB1; ++c) {
            int idx = c * 64 + t;
            int v = (idx < NB1) ? lenS[idx] : 0;
            int x = v;
#pragma unroll
            for (int d = 1; d < 64; d <<= 1) { int y = __shfl_up(x, d, 64); if (t >= d) x += y; }
            if (idx < NB1) offS[idx] = carry + x - v;
            carry += __shfl(x, 63, 64);
        }
        if (t == 0) offS[NB1 < 512 ? NB1 : 512] = carry;
    }
    __syncthreads();
    const int total = min(offS[NB1 < 512 ? NB1 : 512], BCAP);

    for (int blk = t; blk < NB1; blk += 256) {
        int s0 = segdesc[(size_t)blk * SDS + b];
        int l = lenS[blk], o = offS[blk];
        if (o + l > BCAP) l = max(0, BCAP - o);
        const unsigned* sp = packed + (size_t)blk * EPB + s0;
        for (int j = 0; j < l; ++j) ev[o + j] = sp[j];
    }
    __syncthreads();

    for (int i = t; i < total; i += 256) atomicAdd(&hist[(ev[i] >> 16) & 0xFF], 1);
    __syncthreads();

    if (t < 64) {  // wave 0: exclusive scan of hist[0..256)
        int carry = 0;
#pragma unroll
        for (int c = 0; c < 4; ++c) {
            int idx = c * 64 + t;
            int v = hist[idx];
            int x = v;
#pragma unroll
            for (int d = 1; d < 64; d <<= 1) { int y = __shfl_up(x, d, 64); if (t >= d) x += y; }
            excl[idx] = carry + x - v;
            carry += __shfl(x, 63, 64);
        }
        if (t == 0) excl[NBINS] = carry;
    }
    __syncthreads();

    if (t < NBINS) {
        int d = b * NBINS + t;
        if (d < N) {
            int c = hist[t];
            int base = b * BCAP + excl[t];
            rpB[d] = base;
            rpE[d] = base + c;
            dinv[d] = rsqrtf((float)(c + 1));   // +1 self-loop
        }
    }
    for (int i = t; i < total; i += 256) {
        unsigned v = ev[i];
        int l = (v >> 16) & 0xFF;
        int p = excl[l] + atomicAdd(&cur[l], 1);
        se[p] = (unsigned short)(v & 0xFFFF);
    }
    __syncthreads();
    for (int i = t; i < total; i += 256) eidx[(size_t)b * BCAP + i] = se[i];
}

// ---------------- GEMM1 (MFMA): m1p = bf16((x @ W1) * dinv[row]) ----------------

__launch_bounds__(256)
__global__ void k_gemm1(const float* __restrict__ x, const float* __restrict__ W1,
                        const float* __restrict__ dinv,
                        unsigned short* __restrict__ m1p, int N) {
    __shared__ __align__(16) unsigned short xb[64][136];
    __shared__ __align__(16) unsigned short wb[64][136];
    const int t    = threadIdx.x;
    const int lane = t & 63;
    const int wv   = t >> 6;        // wave id 0..3 -> col strip
    const int lr   = lane & 15;     // fragment row (A) / col (B)
    const int kg   = lane >> 4;     // k-group 0..3
    const int row0 = blockIdx.x * 64;

    f32x4 acc[4];
#pragma unroll
    for (int rb = 0; rb < 4; rb++) acc[rb] = (f32x4){0.f, 0.f, 0.f, 0.f};

    for (int k0 = 0; k0 < F_IN; k0 += 128) {
        // stage x chunk: 64 rows x 128 k, f32 -> bf16. 1024 groups of 8.
#pragma unroll
        for (int i = 0; i < 4; i++) {
            int g  = t + i * 256;
            int r  = g >> 4;              // row in tile
            int gk = (g & 15) << 3;       // k offset in chunk
            int row = row0 + r;
            short8v p = (short8v){0, 0, 0, 0, 0, 0, 0, 0};
            if (row < N) {
                const float* sp = &x[(size_t)row * F_IN + k0 + gk];
                float4 f0 = *reinterpret_cast<const float4*>(sp);
                float4 f1 = *reinterpret_cast<const float4*>(sp + 4);
                p[0] = (short)f2bf(f0.x); p[1] = (short)f2bf(f0.y);
                p[2] = (short)f2bf(f0.z); p[3] = (short)f2bf(f0.w);
                p[4] = (short)f2bf(f1.x); p[5] = (short)f2bf(f1.y);
                p[6] = (short)f2bf(f1.z); p[7] = (short)f2bf(f1.w);
            }
            *reinterpret_cast<short8v*>(&xb[r][gk]) = p;
        }
        // stage W chunk transposed: wb[col][k], k in [0,128). 1024 groups of 8 cols.
#pragma unroll
        for (int i = 0; i < 4; i++) {
            int g  = t + i * 256;
            int k  = g >> 3;              // k in chunk
            int c0 = (g & 7) << 3;        // col base
            const float* sp = &W1[(size_t)(k0 + k) * 64 + c0];
            float4 f0 = *reinterpret_cast<const float4*>(sp);
            float4 f1 = *reinterpret_cast<const float4*>(sp + 4);
            wb[c0 + 0][k] = f2bf(f0.x); wb[c0 + 1][k] = f2bf(f0.y);
            wb[c0 + 2][k] = f2bf(f0.z); wb[c0 + 3][k] = f2bf(f0.w);
            wb[c0 + 4][k] = f2bf(f1.x); wb[c0 + 5][k] = f2bf(f1.y);
            wb[c0 + 6][k] = f2bf(f1.z); wb[c0 + 7][k] = f2bf(f1.w);
        }
        __syncthreads();

#pragma unroll
        for (int kk = 0; kk < 128; kk += 32) {
            short8v bfrag = *reinterpret_cast<const short8v*>(&wb[(wv << 4) + lr][kk + (kg << 3)]);
#pragma unroll
            for (int rb = 0; rb < 4; rb++) {
                short8v afrag = *reinterpret_cast<const short8v*>(&xb[(rb << 4) + lr][kk + (kg << 3)]);
                acc[rb] = __builtin_amdgcn_mfma_f32_16x16x32_bf16(afrag, bfrag, acc[rb], 0, 0, 0);
            }
        }
        __syncthreads();
    }

    const int col = (wv << 4) + lr;
#pragma unroll
    for (int rb = 0; rb < 4; rb++) {
#pragma unroll
        for (int i = 0; i < 4; i++) {
            int row = row0 + (rb << 4) + (kg << 2) + i;
            if (row < N) m1p[(size_t)row * 64 + col] = f2bf(acc[rb][i] * dinv[row]);
        }
    }
}

// ---------------- CSR gather, 64 bf16 features: half-wave per node, uint loads ----------------

__launch_bounds__(256)
__global__ void k_gather64h(const int* __restrict__ rpB, const int* __restrict__ rpE,
                            const unsigned short* __restrict__ eidx,
                            const unsigned* __restrict__ msg,   // [N][32] packed bf16 pairs
                            float* __restrict__ acc, int N) {
    int w = blockIdx.x * 8 + (threadIdx.x >> 5);
    if (w >= N) return;
    int f = threadIdx.x & 31;
    int i = rpB[w], e = rpE[w];
    unsigned u = msg[(size_t)w * 32 + f];           // self-loop
    float l0 = bflo(u), h0 = bfhi(u);
    float l1 = 0.f, h1 = 0.f, l2 = 0.f, h2 = 0.f, l3 = 0.f, h3 = 0.f;
    for (; i + 4 <= e; i += 4) {
        unsigned u0 = msg[(size_t)eidx[i]     * 32 + f];
        unsigned u1 = msg[(size_t)eidx[i + 1] * 32 + f];
        unsigned u2 = msg[(size_t)eidx[i + 2] * 32 + f];
        unsigned u3 = msg[(size_t)eidx[i + 3] * 32 + f];
        l0 += bflo(u0); h0 += bfhi(u0);
        l1 += bflo(u1); h1 += bfhi(u1);
        l2 += bflo(u2); h2 += bfhi(u2);
        l3 += bflo(u3); h3 += bfhi(u3);
    }
    for (; i < e; i++) {
        unsigned u0 = msg[(size_t)eidx[i] * 32 + f];
        l0 += bflo(u0); h0 += bfhi(u0);
    }
    *reinterpret_cast<float2*>(&acc[(size_t)w * 64 + (f << 1)]) =
        make_float2((l0 + l1) + (l2 + l3), (h0 + h1) + (h2 + h3));
}

// ---------------- CSR gather, 32 bf16 features: 16 lanes per node, uint loads ----------------
// bias != null: fused mid-layer epilogue h' = bf16(relu(r*s + b) * s) packed to outp.
// bias == null (final pass): write g = bf16(r*s) packed (A-operand-ready for k_out)
//   AND compute out[:,384] = g . W3[:,384] + b3[384] via 16-lane shfl reduce.

__launch_bounds__(256)
__global__ void k_gather32h(const int* __restrict__ rpB, const int* __restrict__ rpE,
                            const unsigned short* __restrict__ eidx,
                            const unsigned* __restrict__ msg,   // [N][16] packed bf16 pairs
                            void* __restrict__ outp, int N,
                            const float* __restrict__ bias, const float* __restrict__ dinv,
                            const float* __restrict__ W3, const float* __restrict__ b3,
                            float* __restrict__ out) {
    int w = blockIdx.x * 16 + (threadIdx.x >> 4);
    if (w >= N) return;
    int f = threadIdx.x & 15;
    int i = rpB[w], e = rpE[w];
    unsigned u = msg[(size_t)w * 16 + f];           // self-loop
    float l0 = bflo(u), h0 = bfhi(u);
    float l1 = 0.f, h1 = 0.f, l2 = 0.f, h2 = 0.f, l3 = 0.f, h3 = 0.f;
    for (; i + 4 <= e; i += 4) {
        unsigned u0 = msg[(size_t)eidx[i]     * 16 + f];
        unsigned u1 = msg[(size_t)eidx[i + 1] * 16 + f];
        unsigned u2 = msg[(size_t)eidx[i + 2] * 16 + f];
        unsigned u3 = msg[(size_t)eidx[i + 3] * 16 + f];
        l0 += bflo(u0); h0 += bfhi(u0);
        l1 += bflo(u1); h1 += bfhi(u1);
        l2 += bflo(u2); h2 += bfhi(u2);
        l3 += bflo(u3); h3 += bfhi(u3);
    }
    for (; i < e; i++) {
        unsigned u0 = msg[(size_t)eidx[i] * 16 + f];
        l0 += bflo(u0); h0 += bfhi(u0);
    }
    float rl = (l0 + l1) + (l2 + l3);
    float rh = (h0 + h1) + (h2 + h3);
    float s = dinv[w];
    if (bias) {
        rl = fmaxf(rl * s + bias[(f << 1)], 0.f) * s;
        rh = fmaxf(rh * s + bias[(f << 1) + 1], 0.f) * s;
        ((unsigned*)outp)[(size_t)w * 16 + f] = (unsigned)f2bf(rl) | ((unsigned)f2bf(rh) << 16);
    } else {
        float gl = rl * s, gh = rh * s;
        ((unsigned*)outp)[(size_t)w * 16 + f] = (unsigned)f2bf(gl) | ((unsigned)f2bf(gh) << 16);
        // fused column 384 of the output GEMM (f32 precision)
        float p = gl * W3[(size_t)(2 * f) * 385 + 384] + gh * W3[(size_t)(2 * f + 1) * 385 + 384];
#pragma unroll
        for (int m = 8; m >= 1; m >>= 1) p += __shfl_xor(p, m, 64);   // 16-lane group reduce
        if (f == 0) out[(size_t)w * 385 + 384] = p + b3[384];
    }
}

// ---------------- layer2: h1 = relu(s*acc1 + b1); m2p = bf16((h1@W2)*s) ----------------

__launch_bounds__(256)
__global__ void k_layer2(const float* __restrict__ acc1, const float* __restrict__ W2,
                         const float* __restrict__ b1, const float* __restrict__ dinv,
                         unsigned short* __restrict__ m2p, int N) {
    __shared__ float h1t[64][64];
    __shared__ float w2t[64][32];
    const int t = threadIdx.x;
    const int row0 = blockIdx.x * 64;
#pragma unroll
    for (int i = 0; i < 16; i++) {
        int lin = i * 256 + t;
        int r = lin >> 6, c = lin & 63;
        int row = row0 + r;
        float v = 0.f;
        if (row < N) v = fmaxf(acc1[(size_t)row * 64 + c] * dinv[row] + b1[c], 0.f);
        h1t[r][c] = v;
    }
#pragma unroll
    for (int i = 0; i < 8; i++) {
        int lin = i * 256 + t;
        w2t[lin >> 5][lin & 31] = W2[lin];
    }
    __syncthreads();
    const int tx = t & 31, ty = t >> 5;
#pragma unroll
    for (int rr = 0; rr < 8; rr++) {
        int r = rr * 8 + ty;
        float a = 0.f;
#pragma unroll
        for (int k = 0; k < 64; k++) a += h1t[r][k] * w2t[k][tx];
        int row = row0 + r;
        if (row < N) m2p[(size_t)row * 32 + tx] = f2bf(a * dinv[row]);
    }
}

// ---------------- out GEMM (MFMA, LDS-free): out[:, 0:384] = g @ W3 + b3; sigmoid col 0 ----------------
// g pre-scaled bf16 [N][16] u32 (A-operand-ready). Grid (ceil(N/64), 6); 4 waves = 4 col strips.
// A frag: one 16B global load per (rb). B frag: 8 scalar L2-hit W3 loads + f2bf.
// Same lane map as k_gemm1 (verified): A row=lr k=8kg+i; C/D row=kg*4+i, col=lr.

__launch_bounds__(256)
__global__ void k_out(const unsigned* __restrict__ gbf, const float* __restrict__ W3,
                      const float* __restrict__ b3, float* __restrict__ out, int N) {
    const int t    = threadIdx.x;
    const int lane = t & 63;
    const int wv   = t >> 6;
    const int lr   = lane & 15;
    const int kg   = lane >> 4;
    const int row0 = blockIdx.x * 64;
    const int col  = blockIdx.y * 64 + (wv << 4) + lr;   // always < 384

    short8v bfrag;
#pragma unroll
    for (int j = 0; j < 8; j++)
        bfrag[j] = (short)f2bf(W3[(size_t)((kg << 3) + j) * 385 + col]);
    const float bias = b3[col];

#pragma unroll
    for (int rb = 0; rb < 4; rb++) {
        int arow = row0 + (rb << 4) + lr;
        short8v afrag = (short8v){0, 0, 0, 0, 0, 0, 0, 0};
        if (arow < N)
            afrag = *reinterpret_cast<const short8v*>(&gbf[(size_t)arow * 16 + (kg << 2)]);
        f32x4 acc = (f32x4){0.f, 0.f, 0.f, 0.f};
        acc = __builtin_amdgcn_mfma_f32_16x16x32_bf16(afrag, bfrag, acc, 0, 0, 0);
#pragma unroll
        for (int i = 0; i < 4; i++) {
            int row = row0 + (rb << 4) + (kg << 2) + i;
            if (row < N) {
                float v = acc[i] + bias;
                if (col == 0) v = 1.0f / (1.0f + expf(-v));
                out[(size_t)row * 385 + col] = v;
            }
        }
    }
}

extern "C" void kernel_launch(void* const* d_in, const int* in_sizes, int n_in,
                              void* d_out, int out_size, void* d_ws, size_t ws_size,
                              hipStream_t stream) {
    const float* x  = (const float*)d_in[0];
    const int*   ei = (const int*)d_in[1];
    const float* W1 = (const float*)d_in[2];
    const float* b1 = (const float*)d_in[3];
    const float* W2 = (const float*)d_in[4];
    const float* b2 = (const float*)d_in[5];
    const float* W3 = (const float*)d_in[6];
    const float* b3 = (const float*)d_in[7];
    float* out = (float*)d_out;

    const int N = in_sizes[0] / F_IN;   // 50000
    const int E = in_sizes[1] / 2;      // 1600000
    const int NB1 = (E + EPB - 1) / EPB;       // 391 pass-1 blocks
    const int NBK = (N + NBINS - 1) / NBINS;   // 196 coarse buckets

    float* ws   = (float*)d_ws;
    float* dinv = ws;
    float* bufA = ws + N;
    float* bufB = bufA + (size_t)64 * N;
    int*   rpB  = (int*)(bufB + (size_t)64 * N);
    int*   rpE  = rpB + N;
    unsigned short* eidx    = (unsigned short*)(rpE + N);
    unsigned short* segdesc = eidx + (size_t)NBK * BCAP;

    unsigned* packed = (unsigned*)bufA;              // E u32; dead after k_p2
    unsigned short* m1p = (unsigned short*)bufA;     // [N,64] bf16 (6.4 MB)
    float* acc1 = bufB;                              // [N,64] f32
    unsigned short* m2p = (unsigned short*)bufA;     // [N,32] bf16
    unsigned short* h2p = (unsigned short*)bufB;     // [N,32] bf16 (acc1 dead)
    unsigned* gbf = (unsigned*)(bufA + (size_t)32 * N);  // [N,16] u32 packed bf16 g (pre-scaled)

    k_p1<<<NB1, 256, 0, stream>>>(ei, E, NBK, packed, segdesc);
    k_p2<<<NBK, 256, 0, stream>>>(packed, segdesc, NB1, eidx, rpB, rpE, dinv, N);

    k_gemm1    <<<(N + 63) / 64, 256, 0, stream>>>(x, W1, dinv, m1p, N);
    k_gather64h<<<(N + 7) / 8, 256, 0, stream>>>(rpB, rpE, eidx, (const unsigned*)m1p, acc1, N);

    k_layer2   <<<(N + 63) / 64, 256, 0, stream>>>(acc1, W2, b1, dinv, m2p, N);
    k_gather32h<<<(N + 15) / 16, 256, 0, stream>>>(rpB, rpE, eidx, (const unsigned*)m2p,
                                                   (void*)h2p, N, b2, dinv, nullptr, nullptr, nullptr);

    k_gather32h<<<(N + 15) / 16, 256, 0, stream>>>(rpB, rpE, eidx, (const unsigned*)h2p,
                                                   (void*)gbf, N, nullptr, dinv, W3, b3, out);

    dim3 gout((N + 63) / 64, 6);
    k_out<<<gout, 256, 0, stream>>>(gbf, W3, b3, out, N);
}

// Round 11
// 154.225 us; speedup vs baseline: 2.3250x; 1.1427x over previous
//
#include <hip/hip_runtime.h>

#define F_IN  384
#define EPB   4096   // edges per block, pass 1
#define NBINS 256    // dsts per coarse bucket
#define BCAP  12288  // eidx region stride per bucket (avg 8163, huge safety margin)
#define SDS   208    // segdesc row stride (u16 entries), >= NBK+1

typedef __attribute__((ext_vector_type(8))) short short8v;   // bf16x8 MFMA fragment
typedef __attribute__((ext_vector_type(4))) float f32x4;     // MFMA accumulator

// bf16 helpers (RNE), no header-type dependence
__device__ __forceinline__ unsigned short f2bf(float f) {
    unsigned u = __float_as_uint(f);
    return (unsigned short)((u + 0x7FFFu + ((u >> 16) & 1u)) >> 16);
}
__device__ __forceinline__ float bflo(unsigned u) { return __uint_as_float(u << 16); }
__device__ __forceinline__ float bfhi(unsigned u) { return __uint_as_float(u & 0xFFFF0000u); }

// ---------------- pass 1: coarse bucket partition (dst>>8), atomic-free ----------------

__launch_bounds__(256)
__global__ void k_p1(const int* __restrict__ ei, int E, int NBK,
                     unsigned* __restrict__ packed, unsigned short* __restrict__ segdesc) {
    __shared__ unsigned sin[EPB];
    __shared__ unsigned sout[EPB];
    __shared__ int hist[257], cur[256], excl[257];
    const int t = threadIdx.x;
    const int e0 = blockIdx.x * EPB;
    const int cnt = min(EPB, E - e0);

    if (t < 256) { hist[t] = 0; cur[t] = 0; }
    if (t == 0) hist[256] = 0;
    __syncthreads();

    for (int i = t; i < cnt; i += 256) {
        int s = ei[e0 + i];
        int d = ei[E + e0 + i];
        sin[i] = ((unsigned)d << 16) | (unsigned)s;   // N < 65536 for both
        atomicAdd(&hist[d >> 8], 1);
    }
    __syncthreads();

    if (t < 64) {  // wave 0: exclusive scan of hist[0..NBK)
        int carry = 0;
        for (int c = 0; c * 64 < NBK; ++c) {
            int idx = c * 64 + t;
            int v = (idx < NBK) ? hist[idx] : 0;
            int x = v;
#pragma unroll
            for (int d = 1; d < 64; d <<= 1) { int y = __shfl_up(x, d, 64); if (t >= d) x += y; }
            if (idx < NBK) excl[idx] = carry + x - v;
            carry += __shfl(x, 63, 64);
        }
        if (t == 0) excl[NBK] = carry;   // == cnt
    }
    __syncthreads();

    for (int i = t; i < cnt; i += 256) {
        unsigned v = sin[i];
        int b = v >> 24;                 // dst >> 8
        int pos = excl[b] + atomicAdd(&cur[b], 1);   // LDS atomic (fast)
        sout[pos] = v;
    }
    __syncthreads();

    for (int i = t; i < cnt; i += 256) packed[(size_t)e0 + i] = sout[i];   // coalesced
    for (int i = t; i <= NBK; i += 256) segdesc[(size_t)blockIdx.x * SDS + i] = (unsigned short)excl[i];
}

// ---------------- pass 2: per-bucket exact CSR (rpB/rpE/dinv/eidx), all in LDS ----------------

__launch_bounds__(256)
__global__ void k_p2(const unsigned* __restrict__ packed, const unsigned short* __restrict__ segdesc,
                     int NB1, unsigned short* __restrict__ eidx,
                     int* __restrict__ rpB, int* __restrict__ rpE,
                     float* __restrict__ dinv, int N) {
    __shared__ unsigned ev[BCAP];
    __shared__ unsigned short se[BCAP];
    __shared__ int lenS[512], offS[513];
    __shared__ int hist[NBINS], cur[NBINS], excl[NBINS + 1];
    const int t = threadIdx.x;
    const int b = blockIdx.x;

    if (t < NBINS) { hist[t] = 0; cur[t] = 0; }
    for (int blk = t; blk < NB1; blk += 256) {
        int s0 = segdesc[(size_t)blk * SDS + b];
        int s1 = segdesc[(size_t)blk * SDS + b + 1];
        lenS[blk] = s1 - s0;
    }
    __syncthreads();

    if (t < 64) {  // wave 0: exclusive scan of lenS[0..NB1)
        int carry = 0;
        for (int c = 0; c * 64 < NB1; ++c) {
            int idx = c * 64 + t;
            int v = (idx < NB1) ? lenS[idx] : 0;
            int x = v;
#pragma unroll
            for (int d = 1; d < 64; d <<= 1) { int y = __shfl_up(x, d, 64); if (t >= d) x += y; }
            if (idx < NB1) offS[idx] = carry + x - v;
            carry += __shfl(x, 63, 64);
        }
        if (t == 0) offS[NB1 < 512 ? NB1 : 512] = carry;
    }
    __syncthreads();
    const int total = min(offS[NB1 < 512 ? NB1 : 512], BCAP);

    for (int blk = t; blk < NB1; blk += 256) {
        int s0 = segdesc[(size_t)blk * SDS + b];
        int l = lenS[blk], o = offS[blk];
        if (o + l > BCAP) l = max(0, BCAP - o);
        const unsigned* sp = packed + (size_t)blk * EPB + s0;
        for (int j = 0; j < l; ++j) ev[o + j] = sp[j];
    }
    __syncthreads();

    for (int i = t; i < total; i += 256) atomicAdd(&hist[(ev[i] >> 16) & 0xFF], 1);
    __syncthreads();

    if (t < 64) {  // wave 0: exclusive scan of hist[0..256)
        int carry = 0;
#pragma unroll
        for (int c = 0; c < 4; ++c) {
            int idx = c * 64 + t;
            int v = hist[idx];
            int x = v;
#pragma unroll
            for (int d = 1; d < 64; d <<= 1) { int y = __shfl_up(x, d, 64); if (t >= d) x += y; }
            excl[idx] = carry + x - v;
            carry += __shfl(x, 63, 64);
        }
        if (t == 0) excl[NBINS] = carry;
    }
    __syncthreads();

    if (t < NBINS) {
        int d = b * NBINS + t;
        if (d < N) {
            int c = hist[t];
            int base = b * BCAP + excl[t];
            rpB[d] = base;
            rpE[d] = base + c;
            dinv[d] = rsqrtf((float)(c + 1));   // +1 self-loop
        }
    }
    for (int i = t; i < total; i += 256) {
        unsigned v = ev[i];
        int l = (v >> 16) & 0xFF;
        int p = excl[l] + atomicAdd(&cur[l], 1);
        se[p] = (unsigned short)(v & 0xFFFF);
    }
    __syncthreads();
    for (int i = t; i < total; i += 256) eidx[(size_t)b * BCAP + i] = se[i];
}

// ---------------- GEMM1 (MFMA): m1p = bf16((x @ W1) * dinv[row]) ----------------

__launch_bounds__(256)
__global__ void k_gemm1(const float* __restrict__ x, const float* __restrict__ W1,
                        const float* __restrict__ dinv,
                        unsigned short* __restrict__ m1p, int N) {
    __shared__ __align__(16) unsigned short xb[64][136];
    __shared__ __align__(16) unsigned short wb[64][136];
    const int t    = threadIdx.x;
    const int lane = t & 63;
    const int wv   = t >> 6;        // wave id 0..3 -> col strip
    const int lr   = lane & 15;     // fragment row (A) / col (B)
    const int kg   = lane >> 4;     // k-group 0..3
    const int row0 = blockIdx.x * 64;

    f32x4 acc[4];
#pragma unroll
    for (int rb = 0; rb < 4; rb++) acc[rb] = (f32x4){0.f, 0.f, 0.f, 0.f};

    for (int k0 = 0; k0 < F_IN; k0 += 128) {
        // stage x chunk: 64 rows x 128 k, f32 -> bf16. 1024 groups of 8.
#pragma unroll
        for (int i = 0; i < 4; i++) {
            int g  = t + i * 256;
            int r  = g >> 4;              // row in tile
            int gk = (g & 15) << 3;       // k offset in chunk
            int row = row0 + r;
            short8v p = (short8v){0, 0, 0, 0, 0, 0, 0, 0};
            if (row < N) {
                const float* sp = &x[(size_t)row * F_IN + k0 + gk];
                float4 f0 = *reinterpret_cast<const float4*>(sp);
                float4 f1 = *reinterpret_cast<const float4*>(sp + 4);
                p[0] = (short)f2bf(f0.x); p[1] = (short)f2bf(f0.y);
                p[2] = (short)f2bf(f0.z); p[3] = (short)f2bf(f0.w);
                p[4] = (short)f2bf(f1.x); p[5] = (short)f2bf(f1.y);
                p[6] = (short)f2bf(f1.z); p[7] = (short)f2bf(f1.w);
            }
            *reinterpret_cast<short8v*>(&xb[r][gk]) = p;
        }
        // stage W chunk transposed: wb[col][k], k in [0,128). 1024 groups of 8 cols.
#pragma unroll
        for (int i = 0; i < 4; i++) {
            int g  = t + i * 256;
            int k  = g >> 3;              // k in chunk
            int c0 = (g & 7) << 3;        // col base
            const float* sp = &W1[(size_t)(k0 + k) * 64 + c0];
            float4 f0 = *reinterpret_cast<const float4*>(sp);
            float4 f1 = *reinterpret_cast<const float4*>(sp + 4);
            wb[c0 + 0][k] = f2bf(f0.x); wb[c0 + 1][k] = f2bf(f0.y);
            wb[c0 + 2][k] = f2bf(f0.z); wb[c0 + 3][k] = f2bf(f0.w);
            wb[c0 + 4][k] = f2bf(f1.x); wb[c0 + 5][k] = f2bf(f1.y);
            wb[c0 + 6][k] = f2bf(f1.z); wb[c0 + 7][k] = f2bf(f1.w);
        }
        __syncthreads();

#pragma unroll
        for (int kk = 0; kk < 128; kk += 32) {
            short8v bfrag = *reinterpret_cast<const short8v*>(&wb[(wv << 4) + lr][kk + (kg << 3)]);
#pragma unroll
            for (int rb = 0; rb < 4; rb++) {
                short8v afrag = *reinterpret_cast<const short8v*>(&xb[(rb << 4) + lr][kk + (kg << 3)]);
                acc[rb] = __builtin_amdgcn_mfma_f32_16x16x32_bf16(afrag, bfrag, acc[rb], 0, 0, 0);
            }
        }
        __syncthreads();
    }

    const int col = (wv << 4) + lr;
#pragma unroll
    for (int rb = 0; rb < 4; rb++) {
#pragma unroll
        for (int i = 0; i < 4; i++) {
            int row = row0 + (rb << 4) + (kg << 2) + i;
            if (row < N) m1p[(size_t)row * 64 + col] = f2bf(acc[rb][i] * dinv[row]);
        }
    }
}

// ---------------- gather64 + layer-1 epilogue: m1h = bf16(relu(s*agg + b1)) ----------------
// half-wave per node; unroll 8 (16 independent f32 chains). Output packed [N][32] u32.

__launch_bounds__(256)
__global__ void k_g64l1(const int* __restrict__ rpB, const int* __restrict__ rpE,
                        const unsigned short* __restrict__ eidx,
                        const unsigned* __restrict__ msg,   // [N][32] packed bf16 pairs
                        const float* __restrict__ b1, const float* __restrict__ dinv,
                        unsigned* __restrict__ m1h, int N) {
    int w = blockIdx.x * 8 + (threadIdx.x >> 5);
    if (w >= N) return;
    int f = threadIdx.x & 31;
    int i = rpB[w], e = rpE[w];
    unsigned u = msg[(size_t)w * 32 + f];           // self-loop
    float l0 = bflo(u), h0 = bfhi(u);
    float l1 = 0.f, h1 = 0.f, l2 = 0.f, h2 = 0.f, l3 = 0.f, h3 = 0.f;
    float l4 = 0.f, h4 = 0.f, l5 = 0.f, h5 = 0.f, l6 = 0.f, h6 = 0.f, l7 = 0.f, h7 = 0.f;
    for (; i + 8 <= e; i += 8) {
        unsigned u0 = msg[(size_t)eidx[i]     * 32 + f];
        unsigned u1 = msg[(size_t)eidx[i + 1] * 32 + f];
        unsigned u2 = msg[(size_t)eidx[i + 2] * 32 + f];
        unsigned u3 = msg[(size_t)eidx[i + 3] * 32 + f];
        unsigned u4 = msg[(size_t)eidx[i + 4] * 32 + f];
        unsigned u5 = msg[(size_t)eidx[i + 5] * 32 + f];
        unsigned u6 = msg[(size_t)eidx[i + 6] * 32 + f];
        unsigned u7 = msg[(size_t)eidx[i + 7] * 32 + f];
        l0 += bflo(u0); h0 += bfhi(u0);  l1 += bflo(u1); h1 += bfhi(u1);
        l2 += bflo(u2); h2 += bfhi(u2);  l3 += bflo(u3); h3 += bfhi(u3);
        l4 += bflo(u4); h4 += bfhi(u4);  l5 += bflo(u5); h5 += bfhi(u5);
        l6 += bflo(u6); h6 += bfhi(u6);  l7 += bflo(u7); h7 += bfhi(u7);
    }
    for (; i + 4 <= e; i += 4) {
        unsigned u0 = msg[(size_t)eidx[i]     * 32 + f];
        unsigned u1 = msg[(size_t)eidx[i + 1] * 32 + f];
        unsigned u2 = msg[(size_t)eidx[i + 2] * 32 + f];
        unsigned u3 = msg[(size_t)eidx[i + 3] * 32 + f];
        l0 += bflo(u0); h0 += bfhi(u0);  l1 += bflo(u1); h1 += bfhi(u1);
        l2 += bflo(u2); h2 += bfhi(u2);  l3 += bflo(u3); h3 += bfhi(u3);
    }
    for (; i < e; i++) {
        unsigned u0 = msg[(size_t)eidx[i] * 32 + f];
        l0 += bflo(u0); h0 += bfhi(u0);
    }
    float suml = ((l0 + l1) + (l2 + l3)) + ((l4 + l5) + (l6 + l7));
    float sumh = ((h0 + h1) + (h2 + h3)) + ((h4 + h5) + (h6 + h7));
    float s = dinv[w];
    float hl = fmaxf(suml * s + b1[(f << 1)], 0.f);
    float hh = fmaxf(sumh * s + b1[(f << 1) + 1], 0.f);
    m1h[(size_t)w * 32 + f] = (unsigned)f2bf(hl) | ((unsigned)f2bf(hh) << 16);
}

// ---------------- CSR gather, 32 bf16 features: 16 lanes per node, unroll 8 ----------------
// bias != null: fused mid-layer epilogue h' = bf16(relu(r*s + b) * s) packed to outp.
// bias == null (final pass): write g = bf16(r*s) packed (A-operand-ready for k_out)
//   AND compute out[:,384] = g . W3[:,384] + b3[384] via 16-lane shfl reduce.

__launch_bounds__(256)
__global__ void k_gather32h(const int* __restrict__ rpB, const int* __restrict__ rpE,
                            const unsigned short* __restrict__ eidx,
                            const unsigned* __restrict__ msg,   // [N][16] packed bf16 pairs
                            void* __restrict__ outp, int N,
                            const float* __restrict__ bias, const float* __restrict__ dinv,
                            const float* __restrict__ W3, const float* __restrict__ b3,
                            float* __restrict__ out) {
    int w = blockIdx.x * 16 + (threadIdx.x >> 4);
    if (w >= N) return;
    int f = threadIdx.x & 15;
    int i = rpB[w], e = rpE[w];
    unsigned u = msg[(size_t)w * 16 + f];           // self-loop
    float l0 = bflo(u), h0 = bfhi(u);
    float l1 = 0.f, h1 = 0.f, l2 = 0.f, h2 = 0.f, l3 = 0.f, h3 = 0.f;
    float l4 = 0.f, h4 = 0.f, l5 = 0.f, h5 = 0.f, l6 = 0.f, h6 = 0.f, l7 = 0.f, h7 = 0.f;
    for (; i + 8 <= e; i += 8) {
        unsigned u0 = msg[(size_t)eidx[i]     * 16 + f];
        unsigned u1 = msg[(size_t)eidx[i + 1] * 16 + f];
        unsigned u2 = msg[(size_t)eidx[i + 2] * 16 + f];
        unsigned u3 = msg[(size_t)eidx[i + 3] * 16 + f];
        unsigned u4 = msg[(size_t)eidx[i + 4] * 16 + f];
        unsigned u5 = msg[(size_t)eidx[i + 5] * 16 + f];
        unsigned u6 = msg[(size_t)eidx[i + 6] * 16 + f];
        unsigned u7 = msg[(size_t)eidx[i + 7] * 16 + f];
        l0 += bflo(u0); h0 += bfhi(u0);  l1 += bflo(u1); h1 += bfhi(u1);
        l2 += bflo(u2); h2 += bfhi(u2);  l3 += bflo(u3); h3 += bfhi(u3);
        l4 += bflo(u4); h4 += bfhi(u4);  l5 += bflo(u5); h5 += bfhi(u5);
        l6 += bflo(u6); h6 += bfhi(u6);  l7 += bflo(u7); h7 += bfhi(u7);
    }
    for (; i + 4 <= e; i += 4) {
        unsigned u0 = msg[(size_t)eidx[i]     * 16 + f];
        unsigned u1 = msg[(size_t)eidx[i + 1] * 16 + f];
        unsigned u2 = msg[(size_t)eidx[i + 2] * 16 + f];
        unsigned u3 = msg[(size_t)eidx[i + 3] * 16 + f];
        l0 += bflo(u0); h0 += bfhi(u0);  l1 += bflo(u1); h1 += bfhi(u1);
        l2 += bflo(u2); h2 += bfhi(u2);  l3 += bflo(u3); h3 += bfhi(u3);
    }
    for (; i < e; i++) {
        unsigned u0 = msg[(size_t)eidx[i] * 16 + f];
        l0 += bflo(u0); h0 += bfhi(u0);
    }
    float rl = ((l0 + l1) + (l2 + l3)) + ((l4 + l5) + (l6 + l7));
    float rh = ((h0 + h1) + (h2 + h3)) + ((h4 + h5) + (h6 + h7));
    float s = dinv[w];
    if (bias) {
        rl = fmaxf(rl * s + bias[(f << 1)], 0.f) * s;
        rh = fmaxf(rh * s + bias[(f << 1) + 1], 0.f) * s;
        ((unsigned*)outp)[(size_t)w * 16 + f] = (unsigned)f2bf(rl) | ((unsigned)f2bf(rh) << 16);
    } else {
        float gl = rl * s, gh = rh * s;
        ((unsigned*)outp)[(size_t)w * 16 + f] = (unsigned)f2bf(gl) | ((unsigned)f2bf(gh) << 16);
        // fused column 384 of the output GEMM (f32 precision)
        float p = gl * W3[(size_t)(2 * f) * 385 + 384] + gh * W3[(size_t)(2 * f + 1) * 385 + 384];
#pragma unroll
        for (int m = 8; m >= 1; m >>= 1) p += __shfl_xor(p, m, 64);   // 16-lane group reduce
        if (f == 0) out[(size_t)w * 385 + 384] = p + b3[384];
    }
}

// ---------------- layer2 (MFMA, LDS-free): m2p = bf16((m1h @ W2) * s) ----------------
// m1h bf16-packed [N][32] u32 (K=64). Grid ceil(N/64); 4 waves = 4 row strips of 16.
// Per wave: 2 col strips x 2 K-halves = 4 MFMA. W2 f32 from L2, cast to bf16.
// Same verified lane map: A row=lr k=8kg+i; C/D row=kg*4+i, col=lr.

__launch_bounds__(256)
__global__ void k_layer2(const unsigned* __restrict__ m1h, const float* __restrict__ W2,
                         const float* __restrict__ dinv,
                         unsigned short* __restrict__ m2p, int N) {
    const int t    = threadIdx.x;
    const int lane = t & 63;
    const int wv   = t >> 6;
    const int lr   = lane & 15;
    const int kg   = lane >> 4;
    const int row0 = blockIdx.x * 64 + (wv << 4);

    short8v b00, b01, b10, b11;   // b[khalf][colstrip]
#pragma unroll
    for (int j = 0; j < 8; j++) {
        int k = (kg << 3) + j;
        b00[j] = (short)f2bf(W2[(size_t)k * 32 + lr]);
        b01[j] = (short)f2bf(W2[(size_t)k * 32 + 16 + lr]);
        b10[j] = (short)f2bf(W2[(size_t)(32 + k) * 32 + lr]);
        b11[j] = (short)f2bf(W2[(size_t)(32 + k) * 32 + 16 + lr]);
    }

    int arow = row0 + lr;
    short8v a0 = (short8v){0, 0, 0, 0, 0, 0, 0, 0};
    short8v a1 = (short8v){0, 0, 0, 0, 0, 0, 0, 0};
    if (arow < N) {
        a0 = *reinterpret_cast<const short8v*>(&m1h[(size_t)arow * 32 + (kg << 2)]);        // k 0..31
        a1 = *reinterpret_cast<const short8v*>(&m1h[(size_t)arow * 32 + 16 + (kg << 2)]);   // k 32..63
    }

    f32x4 accA = (f32x4){0.f, 0.f, 0.f, 0.f};
    f32x4 accB = (f32x4){0.f, 0.f, 0.f, 0.f};
    accA = __builtin_amdgcn_mfma_f32_16x16x32_bf16(a0, b00, accA, 0, 0, 0);
    accA = __builtin_amdgcn_mfma_f32_16x16x32_bf16(a1, b10, accA, 0, 0, 0);
    accB = __builtin_amdgcn_mfma_f32_16x16x32_bf16(a0, b01, accB, 0, 0, 0);
    accB = __builtin_amdgcn_mfma_f32_16x16x32_bf16(a1, b11, accB, 0, 0, 0);

#pragma unroll
    for (int i = 0; i < 4; i++) {
        int row = row0 + (kg << 2) + i;
        if (row < N) {
            float s = dinv[row];
            m2p[(size_t)row * 32 + lr]      = f2bf(accA[i] * s);
            m2p[(size_t)row * 32 + 16 + lr] = f2bf(accB[i] * s);
        }
    }
}

// ---------------- out GEMM (MFMA, LDS-free): out[:, 0:384] = g @ W3 + b3; sigmoid col 0 ----------------

__launch_bounds__(256)
__global__ void k_out(const unsigned* __restrict__ gbf, const float* __restrict__ W3,
                      const float* __restrict__ b3, float* __restrict__ out, int N) {
    const int t    = threadIdx.x;
    const int lane = t & 63;
    const int wv   = t >> 6;
    const int lr   = lane & 15;
    const int kg   = lane >> 4;
    const int row0 = blockIdx.x * 64;
    const int col  = blockIdx.y * 64 + (wv << 4) + lr;   // always < 384

    short8v bfrag;
#pragma unroll
    for (int j = 0; j < 8; j++)
        bfrag[j] = (short)f2bf(W3[(size_t)((kg << 3) + j) * 385 + col]);
    const float bias = b3[col];

#pragma unroll
    for (int rb = 0; rb < 4; rb++) {
        int arow = row0 + (rb << 4) + lr;
        short8v afrag = (short8v){0, 0, 0, 0, 0, 0, 0, 0};
        if (arow < N)
            afrag = *reinterpret_cast<const short8v*>(&gbf[(size_t)arow * 16 + (kg << 2)]);
        f32x4 acc = (f32x4){0.f, 0.f, 0.f, 0.f};
        acc = __builtin_amdgcn_mfma_f32_16x16x32_bf16(afrag, bfrag, acc, 0, 0, 0);
#pragma unroll
        for (int i = 0; i < 4; i++) {
            int row = row0 + (rb << 4) + (kg << 2) + i;
            if (row < N) {
                float v = acc[i] + bias;
                if (col == 0) v = 1.0f / (1.0f + expf(-v));
                out[(size_t)row * 385 + col] = v;
            }
        }
    }
}

extern "C" void kernel_launch(void* const* d_in, const int* in_sizes, int n_in,
                              void* d_out, int out_size, void* d_ws, size_t ws_size,
                              hipStream_t stream) {
    const float* x  = (const float*)d_in[0];
    const int*   ei = (const int*)d_in[1];
    const float* W1 = (const float*)d_in[2];
    const float* b1 = (const float*)d_in[3];
    const float* W2 = (const float*)d_in[4];
    const float* b2 = (const float*)d_in[5];
    const float* W3 = (const float*)d_in[6];
    const float* b3 = (const float*)d_in[7];
    float* out = (float*)d_out;

    const int N = in_sizes[0] / F_IN;   // 50000
    const int E = in_sizes[1] / 2;      // 1600000
    const int NB1 = (E + EPB - 1) / EPB;       // 391 pass-1 blocks
    const int NBK = (N + NBINS - 1) / NBINS;   // 196 coarse buckets

    float* ws   = (float*)d_ws;
    float* dinv = ws;
    float* bufA = ws + N;
    float* bufB = bufA + (size_t)64 * N;
    int*   rpB  = (int*)(bufB + (size_t)64 * N);
    int*   rpE  = rpB + N;
    unsigned short* eidx    = (unsigned short*)(rpE + N);
    unsigned short* segdesc = eidx + (size_t)NBK * BCAP;

    unsigned* packed = (unsigned*)bufA;              // E u32; dead after k_p2
    unsigned short* m1p = (unsigned short*)bufA;     // [N,64] bf16 (6.4 MB)
    unsigned* m1h = (unsigned*)bufB;                 // [N,32] u32 packed bf16 h1
    unsigned short* m2p = (unsigned short*)bufA;     // [N,32] bf16 (m1p dead)
    unsigned short* h2p = (unsigned short*)bufB;     // [N,32] bf16 (m1h dead)
    unsigned* gbf = (unsigned*)(bufA + (size_t)32 * N);  // [N,16] u32 packed bf16 g (no overlap with m2p)

    k_p1<<<NB1, 256, 0, stream>>>(ei, E, NBK, packed, segdesc);
    k_p2<<<NBK, 256, 0, stream>>>(packed, segdesc, NB1, eidx, rpB, rpE, dinv, N);

    k_gemm1   <<<(N + 63) / 64, 256, 0, stream>>>(x, W1, dinv, m1p, N);
    k_g64l1   <<<(N + 7) / 8, 256, 0, stream>>>(rpB, rpE, eidx, (const unsigned*)m1p, b1, dinv, m1h, N);

    k_layer2  <<<(N + 63) / 64, 256, 0, stream>>>(m1h, W2, dinv, m2p, N);
    k_gather32h<<<(N + 15) / 16, 256, 0, stream>>>(rpB, rpE, eidx, (const unsigned*)m2p,
                                                   (void*)h2p, N, b2, dinv, nullptr, nullptr, nullptr);

    k_gather32h<<<(N + 15) / 16, 256, 0, stream>>>(rpB, rpE, eidx, (const unsigned*)h2p,
                                                   (void*)gbf, N, nullptr, dinv, W3, b3, out);

    dim3 gout((N + 63) / 64, 6);
    k_out<<<gout, 256, 0, stream>>>(gbf, W3, b3, out, N);
}